// Round 4
// baseline (14339.838 us; speedup 1.0000x reference)
//
#include <hip/hip_runtime.h>

#define T_ 256
#define B_ 64
static constexpr float BNS = 0.9999950000374997f; // 1/sqrt(1+1e-5)

__device__ __constant__ int d_perm[25] = {0,1,2,3,20, 4,5,6,7,21,22, 8,9,10,11,23,24, 12,13,14,15, 16,17,18,19};
__device__ __constant__ int d_gstart[5] = {0,5,11,17,21};
__device__ __constant__ int d_gn[5] = {5,6,6,4,4};
// 0-indexed valid skeleton edges (entries (1,0),(0,12),(0,16) of the 1-indexed
// list go out of bounds after -1 and are skipped by the reference)
__device__ __constant__ int d_edges[21][2] = {
  {2,1},{1,19},{19,0},{19,3},{3,4},{4,5},{5,21},{5,6},{6,20},{19,7},
  {7,8},{8,9},{9,23},{9,10},{10,22},{11,12},{12,13},{13,14},{15,16},{16,17},{17,18}};

// ---------------- adjacency (fp64, exact reproduction of _sub_adj) -----------
__global__ void adj_kernel(float* __restrict__ adjout){ // [5][36], row stride = n (compact), zero padded
  if (threadIdx.x != 0 || blockIdx.x != 0) return;
  double fa[25][25];
  for (int i=0;i<25;i++) for (int j=0;j<25;j++) fa[i][j]=0.0;
  for (int e=0;e<21;e++){ int i=d_edges[e][0], j=d_edges[e][1]; fa[i][j]=1.0; fa[j][i]=1.0; }
  for (int i=0;i<25;i++) fa[i][i] += 1.0;
  for (int i=0;i<25;i++){
    double dg=0; for (int j=0;j<25;j++) dg += fa[i][j];
    if (dg==0.0) dg=1.0;
    for (int j=0;j<25;j++) fa[i][j] /= dg;
  }
  for (int g=0; g<5; g++){
    int n = d_gn[g]; int gs = d_gstart[g];
    for (int q=0;q<36;q++) adjout[g*36+q] = 0.f;
    double sa[6][6];
    for (int a=0;a<n;a++) for (int b=0;b<n;b++) sa[a][b] = fa[d_perm[gs+a]][d_perm[gs+b]];
    for (int a=0;a<n;a++) sa[a][a] += 1.0;            // n>1 for all groups
    double deg[6];
    for (int a=0;a<n;a++){ double s=0; for (int b=0;b<n;b++) s += sa[a][b]; deg[a]=s; }
    for (int a=1;a<n;a++) if (deg[a]==1.0){ sa[0][a]=1.0; sa[a][0]=1.0; }
    for (int a=0;a<n;a++){
      double s=0; for (int b=0;b<n;b++) s += sa[a][b];
      if (s==0.0) s=1.0;
      for (int b=0;b<n;b++) adjout[g*36 + a*n + b] = (float)(sa[a][b]/s);
    }
  }
}

__global__ void zero_kernel(float* __restrict__ feat, float* __restrict__ loss){
  int i = blockIdx.x*256 + threadIdx.x;
  if (i < 5*64*64) feat[i] = 0.f;
  if (i == 0) loss[0] = 0.f;
}

// ---------------- parallel weight prep --------------------------------------
__global__ __launch_bounds__(256) void fold_swe(
    const float* __restrict__ sw1, const float* __restrict__ sw2, const float* __restrict__ sw3,
    float* __restrict__ swe1, float* __restrict__ swe2, float* __restrict__ swe3){
  int i = blockIdx.x*256 + threadIdx.x;
  if (i < 20480){ int g=i/4096, r=i%4096;
    swe1[i] = sw1[g*12288 + r] + sw1[g*12288 + 4096 + r] + sw1[g*12288 + 8192 + r];
  } else if (i < 61440){ int j=i-20480; int g=j/8192, r=j%8192;
    swe2[j] = sw2[g*24576 + r] + sw2[g*24576 + 8192 + r] + sw2[g*24576 + 16384 + r];
  } else if (i < 102400){ int j=i-61440; int g=j/8192, r=j%8192;
    swe3[j] = sw3[g*24576 + r] + sw3[g*24576 + 8192 + r] + sw3[g*24576 + 16384 + r];
  }
}

template<int Cm, int Cout>
__global__ __launch_bounds__(256) void transpose_tw(const float* __restrict__ tw, float* __restrict__ twT){
  int e = blockIdx.x*256 + threadIdx.x;
  if (e >= 5*3*Cm*Cout) return;
  int o = e % Cout;
  int t = e / Cout;
  int m = t % Cm; t /= Cm;
  int k = t % 3; int g = t/3;
  twT[e] = tw[(size_t)g*Cout*Cm*3 + (o*Cm+m)*3 + k];
}

template<int Cm, int Cin, int Cout>
__global__ __launch_bounds__(256) void prep_gemm(
    const float* __restrict__ twT, const float* __restrict__ swe,
    const float* __restrict__ bg, float* __restrict__ WC){
  constexpr int CT = 256/Cout;
  __shared__ float sS[Cm*CT];
  int g = blockIdx.x, k = blockIdx.y, cz = blockIdx.z;
  int tid = threadIdx.x;
  for (int i=tid; i<Cm*CT; i+=256){
    int m = i/CT, cc = i%CT;
    sS[i] = swe[(size_t)g*Cm*Cin + m*Cin + cz*CT + cc];
  }
  __syncthreads();
  int o = tid % Cout, cc = tid / Cout;
  const float* tp = twT + ((size_t)(g*3+k)*Cm)*Cout + o;
  float acc = 0.f;
  #pragma unroll 4
  for (int m=0;m<Cm;m++) acc += tp[(size_t)m*Cout]*sS[m*CT+cc];
  int c = cz*CT + cc;
  WC[(size_t)g*3*Cin*Cout + ((size_t)k*Cin + c)*Cout + o] = bg[g*Cout+o]*BNS*acc;
}

__global__ __launch_bounds__(256) void prep_rw(
    const float* __restrict__ rw2, const float* __restrict__ rg2, const float* __restrict__ bg2,
    const float* __restrict__ rw3, const float* __restrict__ rg3, const float* __restrict__ bg3,
    float* __restrict__ RW2, float* __restrict__ RW3){
  int i = blockIdx.x*256 + threadIdx.x;
  if (i < 40960){ int g=i/8192, r=i%8192, c=r>>7, o=r&127;
    RW2[i] = bg2[g*128+o]*BNS*rg2[g*128+o]*BNS*rw2[(size_t)g*8192 + o*64 + c];
  } else if (i < 81920){ int j=i-40960; int g=j/8192, r=j%8192, c=r>>6, o=r&63;
    RW3[j] = bg3[g*64+o]*BNS*rg3[g*64+o]*BNS*rw3[(size_t)g*8192 + o*128 + c];
  }
}

__global__ __launch_bounds__(128) void prep_bias(
    const float* __restrict__ twT1, const float* __restrict__ twT2, const float* __restrict__ twT3,
    const float* __restrict__ sb1, const float* __restrict__ tb1, const float* __restrict__ bg1, const float* __restrict__ bb1,
    const float* __restrict__ sb2, const float* __restrict__ tb2, const float* __restrict__ bg2, const float* __restrict__ bb2,
    const float* __restrict__ rb2, const float* __restrict__ rg2, const float* __restrict__ rbb2,
    const float* __restrict__ sb3, const float* __restrict__ tb3, const float* __restrict__ bg3, const float* __restrict__ bb3,
    const float* __restrict__ rb3, const float* __restrict__ rg3, const float* __restrict__ rbb3,
    float* __restrict__ B1, float* __restrict__ RS1, float* __restrict__ B2, float* __restrict__ B3){
  __shared__ float sbe[128];
  int g = blockIdx.x, L = blockIdx.y, tid = threadIdx.x;
  if (L == 0){
    if (tid<64) sbe[tid] = sb1[g*192+tid] + sb1[g*192+64+tid] + sb1[g*192+128+tid];
    __syncthreads();
    if (tid<64){ int o=tid; float gsc = bg1[g*64+o]*BNS;
      for (int k=0;k<3;k++){ float s=0.f; const float* tp = twT1 + ((size_t)(g*3+k)*64)*64 + o;
        for (int m=0;m<64;m++) s += tp[m*64]*sbe[m];
        B1[g*256+(k+1)*64+o] = gsc*s; }
      B1[g*256+o] = gsc*tb1[g*64+o] + bb1[g*64+o];
      RS1[g*64+o] = gsc;
    }
  } else if (L == 1){
    sbe[tid] = sb2[g*384+tid] + sb2[g*384+128+tid] + sb2[g*384+256+tid];
    __syncthreads();
    { int o=tid; float gsc = bg2[g*128+o]*BNS; float rgs = rg2[g*128+o]*BNS;
      for (int k=0;k<3;k++){ float s=0.f; const float* tp = twT2 + ((size_t)(g*3+k)*128)*128 + o;
        for (int m=0;m<128;m++) s += tp[m*128]*sbe[m];
        B2[g*512+(k+1)*128+o] = gsc*s; }
      B2[g*512+o] = gsc*(tb2[g*128+o] + rgs*rb2[g*128+o] + rbb2[g*128+o]) + bb2[g*128+o];
    }
  } else {
    if (tid<64) sbe[tid] = sb3[g*192+tid] + sb3[g*192+64+tid] + sb3[g*192+128+tid];
    __syncthreads();
    if (tid<64){ int o=tid; float gsc = bg3[g*64+o]*BNS; float rgs = rg3[g*64+o]*BNS;
      for (int k=0;k<3;k++){ float s=0.f; const float* tp = twT3 + ((size_t)(g*3+k)*64)*64 + o;
        for (int m=0;m<64;m++) s += tp[m*64]*sbe[m];
        B3[g*256+(k+1)*64+o] = gsc*s; }
      B3[g*256+o] = gsc*(tb3[g*64+o] + rgs*rb3[g*64+o] + rbb3[g*64+o]) + bb3[g*64+o];
    }
  }
}

// ---------------- fused ST layer (Cin-chunked, ds-batched inner loops) -------
// MODE 1: embed fused from x, identity residual (scaled), write out
// MODE 2: residual matmul RW, write out (Cout split over blockIdx.z)
// MODE 3: residual matmul RW, fused (T,V)-sum -> atomicAdd into feat
// COS = full Cout stride of W/RW/BV/out; each block computes 64 outputs.
template<int Cin, int COS, int NJ, int MODE>
__global__ __launch_bounds__(256, 4) void st_layer(
    const float* __restrict__ in, float* __restrict__ out,
    const float* __restrict__ W, const float* __restrict__ RW,
    const float* __restrict__ BV, const float* __restrict__ RS,
    const float* __restrict__ adjg, const float* __restrict__ ew,
    const float* __restrict__ eb, int gstart)
{
  constexpr int TC = 16;
  constexpr int SE = (TC+2)*NJ;
  constexpr int SITES = TC*NJ;
  constexpr int SP = SITES/8;
  constexpr int OP = 2;           // 64 outputs per block / 32 o-lanes
  constexpr int NCH = Cin/32;
  __shared__ float sIn[SE*32];
  __shared__ float sXg[SE*32];
  __shared__ float sAdj[NJ*NJ];
  __shared__ float sX3[MODE==1 ? SE*3 : 1];
  const int tid = threadIdx.x;
  const int b = blockIdx.y;
  const int t0 = blockIdx.x*TC;
  const int ooff = blockIdx.z*64;
  W += ooff; BV += ooff;
  if (MODE != 1) RW += ooff;
  if (MODE == 2) out += ooff;

  if (tid < NJ*NJ) sAdj[tid] = adjg[tid];
  if (MODE == 1){
    for (int e=tid; e<SE*3; e+=256){
      int se = e/3, j = e - se*3;
      int tl = se/NJ; int u = se - tl*NJ; int t = t0 + tl - 1;
      float v = 0.f;
      if (t>=0 && t<T_){ int joint = d_perm[gstart+u]; v = in[(((size_t)b*T_ + t)*25 + joint)*3 + j]; }
      sX3[e] = v;
    }
  }

  const int lane = tid & 63;
  const int o = lane & 31;
  const int sg = (tid>>6)*2 + (lane>>5);
  const int s0 = sg*SP;

  float acc[SP][OP];
  {
    float bno[OP], bk0[OP], bk1[OP], bk2[OP];
    #pragma unroll
    for (int j=0;j<OP;j++){ int oj = j*32 + o;
      bno[j]=BV[oj]; bk0[j]=BV[COS+oj]; bk1[j]=BV[2*COS+oj]; bk2[j]=BV[3*COS+oj]; }
    #pragma unroll
    for (int i=0;i<SP;i++){
      int s = s0 + i; int tg = t0 + s/NJ;
      #pragma unroll
      for (int j=0;j<OP;j++)
        acc[i][j] = bno[j] + bk1[j] + (tg>0 ? bk0[j] : 0.f) + (tg<T_-1 ? bk2[j] : 0.f);
    }
  }

  #pragma unroll 1
  for (int cz=0; cz<NCH; ++cz){
    __syncthreads();   // protects prior-chunk reads (and sAdj/sX3 on cz==0)
    // ---- stage input chunk [SE][32]
    if (MODE == 1){
      int cg = cz*32 + (tid & 31);
      float w0 = ew[cg*3], w1 = ew[cg*3+1], w2 = ew[cg*3+2], b0 = eb[cg];
      for (int e=tid; e<SE*32; e+=256){
        int se = e>>5; int t = t0 + se/NJ - 1;
        float v = 0.f;
        if (t>=0 && t<T_) v = b0 + sX3[se*3]*w0 + sX3[se*3+1]*w1 + sX3[se*3+2]*w2;
        sIn[e] = v;
      }
    } else {
      for (int e4=tid; e4<SE*8; e4+=256){
        int se = e4>>3; int cc = (e4&7)<<2;
        int tl = se/NJ; int u = se - tl*NJ; int t = t0 + tl - 1;
        float4 v = make_float4(0.f,0.f,0.f,0.f);
        if (t>=0 && t<T_) v = *(const float4*)&in[(((size_t)b*T_ + t)*NJ + u)*(size_t)Cin + cz*32 + cc];
        *(float4*)&sIn[se*32+cc] = v;
      }
    }
    __syncthreads();
    // ---- xg chunk = adj @ in
    for (int e=tid; e<SE*32; e+=256){
      int se = e>>5; int c = e&31; int u = se%NJ; int base = (se-u)*32 + c;
      float a = 0.f;
      #pragma unroll
      for (int v=0; v<NJ; v++) a += sAdj[u*NJ+v]*sIn[base + v*32];
      sXg[e] = a;
    }
    __syncthreads();
    // ---- partial conv over this chunk (k fully unrolled, ds-reads batched)
    #pragma unroll
    for (int k=0;k<3;k++){
      const float* Wk = W + (size_t)(k*Cin + cz*32)*COS;
      #pragma unroll
      for (int c4=0;c4<32;c4+=4){
        float wv[4][OP];
        #pragma unroll
        for (int q=0;q<4;q++)
          #pragma unroll
          for (int j=0;j<OP;j++) wv[q][j] = Wk[(size_t)(c4+q)*COS + j*32 + o];
        float4 xr[SP];
        #pragma unroll
        for (int i=0;i<SP;i++)
          xr[i] = *(const float4*)&sXg[(s0+i+k*NJ)*32 + c4];
        #pragma unroll
        for (int i=0;i<SP;i++){
          #pragma unroll
          for (int j=0;j<OP;j++)
            acc[i][j] += xr[i].x*wv[0][j] + xr[i].y*wv[1][j] + xr[i].z*wv[2][j] + xr[i].w*wv[3][j];
        }
      }
    }
    // ---- partial residual over this chunk
    if (MODE == 1){
      float rsv = RS[cz*32 + o];     // output channel cz*32+o -> j==cz
      float xr1[SP];
      #pragma unroll
      for (int i=0;i<SP;i++) xr1[i] = sIn[(s0+i+NJ)*32 + o];
      #pragma unroll
      for (int i=0;i<SP;i++)
        acc[i][cz] += xr1[i]*rsv;
    } else {
      #pragma unroll
      for (int c4=0;c4<32;c4+=4){
        float rv[4][OP];
        #pragma unroll
        for (int q=0;q<4;q++)
          #pragma unroll
          for (int j=0;j<OP;j++) rv[q][j] = RW[(size_t)(cz*32+c4+q)*COS + j*32 + o];
        float4 xr[SP];
        #pragma unroll
        for (int i=0;i<SP;i++)
          xr[i] = *(const float4*)&sIn[(s0+i+NJ)*32 + c4];
        #pragma unroll
        for (int i=0;i<SP;i++){
          #pragma unroll
          for (int j=0;j<OP;j++)
            acc[i][j] += xr[i].x*rv[0][j] + xr[i].y*rv[1][j] + xr[i].z*rv[2][j] + xr[i].w*rv[3][j];
        }
      }
    }
  }
  // ---- epilogue
  if (MODE == 3){
    #pragma unroll
    for (int j=0;j<OP;j++){
      float sum = 0.f;
      #pragma unroll
      for (int i=0;i<SP;i++) sum += fmaxf(acc[i][j], 0.f);
      atomicAdd(&out[(size_t)b*64 + j*32 + o], sum);
    }
  } else {
    size_t obase = ((size_t)b*T_ + t0)*NJ*COS;
    #pragma unroll
    for (int i=0;i<SP;i++)
      #pragma unroll
      for (int j=0;j<OP;j++)
        out[obase + (size_t)(s0+i)*COS + j*32 + o] = fmaxf(acc[i][j], 0.f);
  }
}

// ---------------- VQ ---------------------------------------------------------
__global__ __launch_bounds__(128) void vq_kernel(const float* __restrict__ feat,
    const float* __restrict__ cb, float* __restrict__ dout){
  int b = blockIdx.x, g = blockIdx.y, tid = threadIdx.x;
  __shared__ float sF[64];
  __shared__ float sD[128]; __shared__ int sI[128];
  __shared__ float sL[64];
  float inv = 1.0f/(256.0f*(float)d_gn[g]);
  if (tid < 64) sF[tid] = feat[((size_t)g*64 + b)*64 + tid]*inv;
  __syncthreads();
  const float* cbg = cb + (size_t)g*128*64;
  {
    const float* c = cbg + (size_t)tid*64;
    float d = 0.f;
    for (int i=0;i<64;i++){ float df = c[i]-sF[i]; d += df*df; }
    sD[tid] = d; sI[tid] = tid;
  }
  __syncthreads();
  for (int s=64; s>0; s>>=1){
    if (tid < s){
      float d2 = sD[tid+s]; int i2 = sI[tid+s];
      if (d2 < sD[tid] || (d2 == sD[tid] && i2 < sI[tid])){ sD[tid]=d2; sI[tid]=i2; }
    }
    __syncthreads();
  }
  int idx = sI[0];
  if (tid < 64){
    float q = cbg[(size_t)idx*64 + tid];
    dout[((size_t)g*64 + b)*64 + tid] = q;
    float df = q - sF[tid];
    sL[tid] = df*df;
  }
  __syncthreads();
  if (tid == 0){
    float s = 0.f;
    for (int i=0;i<64;i++) s += sL[i];
    atomicAdd(dout + 20480, 1.25f*s/4096.0f);
    dout[20481 + g*64 + b] = (float)idx;
  }
}

// ---------------- dispatch helpers ------------------------------------------
static void launch_st1(int nj, hipStream_t s, const float* x, float* A1,
    const float* WC, const float* BV, const float* RS, const float* adj,
    const float* ew, const float* eb, int gstart){
  dim3 grid(T_/16, B_, 1);
  switch(nj){
    case 4: st_layer<64,64,4,1><<<grid,256,0,s>>>(x,A1,WC,nullptr,BV,RS,adj,ew,eb,gstart); break;
    case 5: st_layer<64,64,5,1><<<grid,256,0,s>>>(x,A1,WC,nullptr,BV,RS,adj,ew,eb,gstart); break;
    case 6: st_layer<64,64,6,1><<<grid,256,0,s>>>(x,A1,WC,nullptr,BV,RS,adj,ew,eb,gstart); break;
  }
}
static void launch_st2(int nj, hipStream_t s, const float* A1, float* A2,
    const float* WC, const float* RW, const float* BV, const float* adj){
  dim3 grid(T_/16, B_, 2);
  switch(nj){
    case 4: st_layer<64,128,4,2><<<grid,256,0,s>>>(A1,A2,WC,RW,BV,nullptr,adj,nullptr,nullptr,0); break;
    case 5: st_layer<64,128,5,2><<<grid,256,0,s>>>(A1,A2,WC,RW,BV,nullptr,adj,nullptr,nullptr,0); break;
    case 6: st_layer<64,128,6,2><<<grid,256,0,s>>>(A1,A2,WC,RW,BV,nullptr,adj,nullptr,nullptr,0); break;
  }
}
static void launch_st3(int nj, hipStream_t s, const float* A2, float* featg,
    const float* WC, const float* RW, const float* BV, const float* adj){
  dim3 grid(T_/16, B_, 1);
  switch(nj){
    case 4: st_layer<128,64,4,3><<<grid,256,0,s>>>(A2,featg,WC,RW,BV,nullptr,adj,nullptr,nullptr,0); break;
    case 5: st_layer<128,64,5,3><<<grid,256,0,s>>>(A2,featg,WC,RW,BV,nullptr,adj,nullptr,nullptr,0); break;
    case 6: st_layer<128,64,6,3><<<grid,256,0,s>>>(A2,featg,WC,RW,BV,nullptr,adj,nullptr,nullptr,0); break;
  }
}

extern "C" void kernel_launch(void* const* d_in, const int* in_sizes, int n_in,
                              void* d_out, int out_size, void* d_ws, size_t ws_size,
                              hipStream_t stream) {
  const float* x    = (const float*)d_in[0];
  const float* ew   = (const float*)d_in[1];
  const float* eb   = (const float*)d_in[2];
  const float* sw1  = (const float*)d_in[3];
  const float* sb1  = (const float*)d_in[4];
  const float* tw1  = (const float*)d_in[5];
  const float* tb1  = (const float*)d_in[6];
  const float* bg1  = (const float*)d_in[7];
  const float* bb1  = (const float*)d_in[8];
  const float* rw2  = (const float*)d_in[9];
  const float* rb2  = (const float*)d_in[10];
  const float* rg2  = (const float*)d_in[11];
  const float* rbb2 = (const float*)d_in[12];
  const float* sw2  = (const float*)d_in[13];
  const float* sb2  = (const float*)d_in[14];
  const float* tw2  = (const float*)d_in[15];
  const float* tb2  = (const float*)d_in[16];
  const float* bg2  = (const float*)d_in[17];
  const float* bb2  = (const float*)d_in[18];
  const float* rw3  = (const float*)d_in[19];
  const float* rb3  = (const float*)d_in[20];
  const float* rg3  = (const float*)d_in[21];
  const float* rbb3 = (const float*)d_in[22];
  const float* sw3  = (const float*)d_in[23];
  const float* sb3  = (const float*)d_in[24];
  const float* tw3  = (const float*)d_in[25];
  const float* tb3  = (const float*)d_in[26];
  const float* bg3  = (const float*)d_in[27];
  const float* bb3  = (const float*)d_in[28];
  const float* cbs  = (const float*)d_in[29];
  float* dout = (float*)d_out;
  float* ws = (float*)d_ws;

  const size_t OFF_ADJ = 0;
  const size_t OFF_WC1 = 256;
  const size_t OFF_B1  = 61696;
  const size_t OFF_RS1 = 62976;
  const size_t OFF_WC2 = 63296;
  const size_t OFF_RW2 = 186176;
  const size_t OFF_B2  = 227136;
  const size_t OFF_WC3 = 229696;
  const size_t OFF_RW3 = 352576;
  const size_t OFF_B3  = 393536;
  const size_t OFF_FEAT= 394816;
  const size_t OFF_A1  = 415296;
  const size_t OFF_A2  = 6706752;
  const size_t WS_FLOATS = 19289664;
  if (ws_size < WS_FLOATS*sizeof(float)) return; // insufficient workspace -> fail loudly at validation

  float* adj5 = ws + OFF_ADJ;
  float* WC1  = ws + OFF_WC1;  float* B1 = ws + OFF_B1;  float* RS1 = ws + OFF_RS1;
  float* WC2  = ws + OFF_WC2;  float* RW2 = ws + OFF_RW2; float* B2 = ws + OFF_B2;
  float* WC3  = ws + OFF_WC3;  float* RW3 = ws + OFF_RW3; float* B3 = ws + OFF_B3;
  float* feat = ws + OFF_FEAT;
  float* A1   = ws + OFF_A1;
  float* A2   = ws + OFF_A2;

  // prep-phase scratch aliased into the A2 region (dead until st2 writes it)
  float* twT1 = A2;            // 61440
  float* twT2 = A2 + 61440;    // 245760
  float* twT3 = A2 + 307200;   // 61440
  float* swe1 = A2 + 368640;   // 20480
  float* swe2 = A2 + 389120;   // 40960
  float* swe3 = A2 + 430080;   // 40960

  zero_kernel<<<80, 256, 0, stream>>>(feat, dout + 20480);
  adj_kernel<<<1, 64, 0, stream>>>(adj5);
  fold_swe<<<400, 256, 0, stream>>>(sw1, sw2, sw3, swe1, swe2, swe3);
  transpose_tw<64,64>  <<<240, 256, 0, stream>>>(tw1, twT1);
  transpose_tw<128,128><<<960, 256, 0, stream>>>(tw2, twT2);
  transpose_tw<64,64>  <<<240, 256, 0, stream>>>(tw3, twT3);
  prep_gemm<64,64,64>  <<<dim3(5,3,16), 256, 0, stream>>>(twT1, swe1, bg1, WC1);
  prep_gemm<128,64,128><<<dim3(5,3,32), 256, 0, stream>>>(twT2, swe2, bg2, WC2);
  prep_gemm<64,128,64> <<<dim3(5,3,32), 256, 0, stream>>>(twT3, swe3, bg3, WC3);
  prep_rw<<<320, 256, 0, stream>>>(rw2, rg2, bg2, rw3, rg3, bg3, RW2, RW3);
  prep_bias<<<dim3(5,3), 128, 0, stream>>>(twT1, twT2, twT3,
      sb1, tb1, bg1, bb1,
      sb2, tb2, bg2, bb2, rb2, rg2, rbb2,
      sb3, tb3, bg3, bb3, rb3, rg3, rbb3,
      B1, RS1, B2, B3);

  const int h_gn[5] = {5,6,6,4,4};
  const int h_gstart[5] = {0,5,11,17,21};
  for (int g=0; g<5; g++){
    int nj = h_gn[g];
    launch_st1(nj, stream, x, A1, WC1 + (size_t)g*12288, B1 + g*256, RS1 + g*64,
               adj5 + g*36, ew, eb, h_gstart[g]);
    launch_st2(nj, stream, A1, A2, WC2 + (size_t)g*24576, RW2 + (size_t)g*8192,
               B2 + g*512, adj5 + g*36);
    launch_st3(nj, stream, A2, feat + (size_t)g*4096, WC3 + (size_t)g*24576,
               RW3 + (size_t)g*8192, B3 + g*256, adj5 + g*36);
  }
  vq_kernel<<<dim3(B_,5), 128, 0, stream>>>(feat, cbs, dout);
}

// Round 5
// 13683.826 us; speedup vs baseline: 1.0479x; 1.0479x over previous
//
#include <hip/hip_runtime.h>

#define T_ 256
#define B_ 64
static constexpr float BNS = 0.9999950000374997f; // 1/sqrt(1+1e-5)

__device__ __constant__ int d_perm[25] = {0,1,2,3,20, 4,5,6,7,21,22, 8,9,10,11,23,24, 12,13,14,15, 16,17,18,19};
__device__ __constant__ int d_gstart[5] = {0,5,11,17,21};
__device__ __constant__ int d_gn[5] = {5,6,6,4,4};
// 0-indexed valid skeleton edges (entries (1,0),(0,12),(0,16) of the 1-indexed
// list go out of bounds after -1 and are skipped by the reference)
__device__ __constant__ int d_edges[21][2] = {
  {2,1},{1,19},{19,0},{19,3},{3,4},{4,5},{5,21},{5,6},{6,20},{19,7},
  {7,8},{8,9},{9,23},{9,10},{10,22},{11,12},{12,13},{13,14},{15,16},{16,17},{17,18}};

// ---------------- adjacency (fp64, exact reproduction of _sub_adj) -----------
__global__ void adj_kernel(float* __restrict__ adjout){ // [5][36], row stride = n (compact), zero padded
  if (threadIdx.x != 0 || blockIdx.x != 0) return;
  double fa[25][25];
  for (int i=0;i<25;i++) for (int j=0;j<25;j++) fa[i][j]=0.0;
  for (int e=0;e<21;e++){ int i=d_edges[e][0], j=d_edges[e][1]; fa[i][j]=1.0; fa[j][i]=1.0; }
  for (int i=0;i<25;i++) fa[i][i] += 1.0;
  for (int i=0;i<25;i++){
    double dg=0; for (int j=0;j<25;j++) dg += fa[i][j];
    if (dg==0.0) dg=1.0;
    for (int j=0;j<25;j++) fa[i][j] /= dg;
  }
  for (int g=0; g<5; g++){
    int n = d_gn[g]; int gs = d_gstart[g];
    for (int q=0;q<36;q++) adjout[g*36+q] = 0.f;
    double sa[6][6];
    for (int a=0;a<n;a++) for (int b=0;b<n;b++) sa[a][b] = fa[d_perm[gs+a]][d_perm[gs+b]];
    for (int a=0;a<n;a++) sa[a][a] += 1.0;            // n>1 for all groups
    double deg[6];
    for (int a=0;a<n;a++){ double s=0; for (int b=0;b<n;b++) s += sa[a][b]; deg[a]=s; }
    for (int a=1;a<n;a++) if (deg[a]==1.0){ sa[0][a]=1.0; sa[a][0]=1.0; }
    for (int a=0;a<n;a++){
      double s=0; for (int b=0;b<n;b++) s += sa[a][b];
      if (s==0.0) s=1.0;
      for (int b=0;b<n;b++) adjout[g*36 + a*n + b] = (float)(sa[a][b]/s);
    }
  }
}

__global__ void zero_kernel(float* __restrict__ feat, float* __restrict__ loss){
  int i = blockIdx.x*256 + threadIdx.x;
  if (i < 5*64*64) feat[i] = 0.f;
  if (i == 0) loss[0] = 0.f;
}

// ---------------- parallel weight prep --------------------------------------
__global__ __launch_bounds__(256) void fold_swe(
    const float* __restrict__ sw1, const float* __restrict__ sw2, const float* __restrict__ sw3,
    float* __restrict__ swe1, float* __restrict__ swe2, float* __restrict__ swe3){
  int i = blockIdx.x*256 + threadIdx.x;
  if (i < 20480){ int g=i/4096, r=i%4096;
    swe1[i] = sw1[g*12288 + r] + sw1[g*12288 + 4096 + r] + sw1[g*12288 + 8192 + r];
  } else if (i < 61440){ int j=i-20480; int g=j/8192, r=j%8192;
    swe2[j] = sw2[g*24576 + r] + sw2[g*24576 + 8192 + r] + sw2[g*24576 + 16384 + r];
  } else if (i < 102400){ int j=i-61440; int g=j/8192, r=j%8192;
    swe3[j] = sw3[g*24576 + r] + sw3[g*24576 + 8192 + r] + sw3[g*24576 + 16384 + r];
  }
}

template<int Cm, int Cout>
__global__ __launch_bounds__(256) void transpose_tw(const float* __restrict__ tw, float* __restrict__ twT){
  int e = blockIdx.x*256 + threadIdx.x;
  if (e >= 5*3*Cm*Cout) return;
  int o = e % Cout;
  int t = e / Cout;
  int m = t % Cm; t /= Cm;
  int k = t % 3; int g = t/3;
  twT[e] = tw[(size_t)g*Cout*Cm*3 + (o*Cm+m)*3 + k];
}

template<int Cm, int Cin, int Cout>
__global__ __launch_bounds__(256) void prep_gemm(
    const float* __restrict__ twT, const float* __restrict__ swe,
    const float* __restrict__ bg, float* __restrict__ WC){
  constexpr int CT = 256/Cout;
  __shared__ float sS[Cm*CT];
  int g = blockIdx.x, k = blockIdx.y, cz = blockIdx.z;
  int tid = threadIdx.x;
  for (int i=tid; i<Cm*CT; i+=256){
    int m = i/CT, cc = i%CT;
    sS[i] = swe[(size_t)g*Cm*Cin + m*Cin + cz*CT + cc];
  }
  __syncthreads();
  int o = tid % Cout, cc = tid / Cout;
  const float* tp = twT + ((size_t)(g*3+k)*Cm)*Cout + o;
  float acc = 0.f;
  #pragma unroll 4
  for (int m=0;m<Cm;m++) acc += tp[(size_t)m*Cout]*sS[m*CT+cc];
  int c = cz*CT + cc;
  WC[(size_t)g*3*Cin*Cout + ((size_t)k*Cin + c)*Cout + o] = bg[g*Cout+o]*BNS*acc;
}

__global__ __launch_bounds__(256) void prep_rw(
    const float* __restrict__ rw2, const float* __restrict__ rg2, const float* __restrict__ bg2,
    const float* __restrict__ rw3, const float* __restrict__ rg3, const float* __restrict__ bg3,
    float* __restrict__ RW2, float* __restrict__ RW3){
  int i = blockIdx.x*256 + threadIdx.x;
  if (i < 40960){ int g=i/8192, r=i%8192, c=r>>7, o=r&127;
    RW2[i] = bg2[g*128+o]*BNS*rg2[g*128+o]*BNS*rw2[(size_t)g*8192 + o*64 + c];
  } else if (i < 81920){ int j=i-40960; int g=j/8192, r=j%8192, c=r>>6, o=r&63;
    RW3[j] = bg3[g*64+o]*BNS*rg3[g*64+o]*BNS*rw3[(size_t)g*8192 + o*128 + c];
  }
}

__global__ __launch_bounds__(128) void prep_bias(
    const float* __restrict__ twT1, const float* __restrict__ twT2, const float* __restrict__ twT3,
    const float* __restrict__ sb1, const float* __restrict__ tb1, const float* __restrict__ bg1, const float* __restrict__ bb1,
    const float* __restrict__ sb2, const float* __restrict__ tb2, const float* __restrict__ bg2, const float* __restrict__ bb2,
    const float* __restrict__ rb2, const float* __restrict__ rg2, const float* __restrict__ rbb2,
    const float* __restrict__ sb3, const float* __restrict__ tb3, const float* __restrict__ bg3, const float* __restrict__ bb3,
    const float* __restrict__ rb3, const float* __restrict__ rg3, const float* __restrict__ rbb3,
    float* __restrict__ B1, float* __restrict__ RS1, float* __restrict__ B2, float* __restrict__ B3){
  __shared__ float sbe[128];
  int g = blockIdx.x, L = blockIdx.y, tid = threadIdx.x;
  if (L == 0){
    if (tid<64) sbe[tid] = sb1[g*192+tid] + sb1[g*192+64+tid] + sb1[g*192+128+tid];
    __syncthreads();
    if (tid<64){ int o=tid; float gsc = bg1[g*64+o]*BNS;
      for (int k=0;k<3;k++){ float s=0.f; const float* tp = twT1 + ((size_t)(g*3+k)*64)*64 + o;
        for (int m=0;m<64;m++) s += tp[m*64]*sbe[m];
        B1[g*256+(k+1)*64+o] = gsc*s; }
      B1[g*256+o] = gsc*tb1[g*64+o] + bb1[g*64+o];
      RS1[g*64+o] = gsc;
    }
  } else if (L == 1){
    sbe[tid] = sb2[g*384+tid] + sb2[g*384+128+tid] + sb2[g*384+256+tid];
    __syncthreads();
    { int o=tid; float gsc = bg2[g*128+o]*BNS; float rgs = rg2[g*128+o]*BNS;
      for (int k=0;k<3;k++){ float s=0.f; const float* tp = twT2 + ((size_t)(g*3+k)*128)*128 + o;
        for (int m=0;m<128;m++) s += tp[m*128]*sbe[m];
        B2[g*512+(k+1)*128+o] = gsc*s; }
      B2[g*512+o] = gsc*(tb2[g*128+o] + rgs*rb2[g*128+o] + rbb2[g*128+o]) + bb2[g*128+o];
    }
  } else {
    if (tid<64) sbe[tid] = sb3[g*192+tid] + sb3[g*192+64+tid] + sb3[g*192+128+tid];
    __syncthreads();
    if (tid<64){ int o=tid; float gsc = bg3[g*64+o]*BNS; float rgs = rg3[g*64+o]*BNS;
      for (int k=0;k<3;k++){ float s=0.f; const float* tp = twT3 + ((size_t)(g*3+k)*64)*64 + o;
        for (int m=0;m<64;m++) s += tp[m*64]*sbe[m];
        B3[g*256+(k+1)*64+o] = gsc*s; }
      B3[g*256+o] = gsc*(tb3[g*64+o] + rgs*rb3[g*64+o] + rbb3[g*64+o]) + bb3[g*64+o];
    }
  }
}

// ---------------- fused ST layer (Cin-chunked, group-batched ds reads) -------
// MODE 1: embed fused from x, identity residual (scaled), write out
// MODE 2: residual matmul RW, write out (Cout split over blockIdx.z)
// MODE 3: residual matmul RW, fused (T,V)-sum -> atomicAdd into feat
// COS = full Cout stride of W/RW/BV/out; each block computes 64 outputs.
template<int Cin, int COS, int NJ, int MODE>
__global__ __launch_bounds__(256, 4) void st_layer(
    const float* __restrict__ in, float* __restrict__ out,
    const float* __restrict__ W, const float* __restrict__ RW,
    const float* __restrict__ BV, const float* __restrict__ RS,
    const float* __restrict__ adjg, const float* __restrict__ ew,
    const float* __restrict__ eb, int gstart)
{
  constexpr int TC = 16;
  constexpr int SE = (TC+2)*NJ;
  constexpr int SITES = TC*NJ;
  constexpr int SP = SITES/8;
  constexpr int OP = 2;            // 64 outputs per block / 32 o-lanes
  constexpr int NCH = Cin/32;
  constexpr int G = (SP%4==0) ? 4 : 2;   // ds-read batch: bounded live range (no spill)
  __shared__ float sIn[SE*32];
  __shared__ float sXg[SE*32];
  __shared__ float sAdj[NJ*NJ];
  __shared__ float sX3[MODE==1 ? SE*3 : 1];
  const int tid = threadIdx.x;
  const int b = blockIdx.y;
  const int t0 = blockIdx.x*TC;
  const int ooff = blockIdx.z*64;
  W += ooff; BV += ooff;
  if (MODE != 1) RW += ooff;
  if (MODE == 2) out += ooff;

  if (tid < NJ*NJ) sAdj[tid] = adjg[tid];
  if (MODE == 1){
    for (int e=tid; e<SE*3; e+=256){
      int se = e/3, j = e - se*3;
      int tl = se/NJ; int u = se - tl*NJ; int t = t0 + tl - 1;
      float v = 0.f;
      if (t>=0 && t<T_){ int joint = d_perm[gstart+u]; v = in[(((size_t)b*T_ + t)*25 + joint)*3 + j]; }
      sX3[e] = v;
    }
  }

  const int lane = tid & 63;
  const int o = lane & 31;
  const int sg = (tid>>6)*2 + (lane>>5);
  const int s0 = sg*SP;

  float acc[SP][OP];
  {
    float bno[OP], bk0[OP], bk1[OP], bk2[OP];
    #pragma unroll
    for (int j=0;j<OP;j++){ int oj = j*32 + o;
      bno[j]=BV[oj]; bk0[j]=BV[COS+oj]; bk1[j]=BV[2*COS+oj]; bk2[j]=BV[3*COS+oj]; }
    #pragma unroll
    for (int i=0;i<SP;i++){
      int s = s0 + i; int tg = t0 + s/NJ;
      #pragma unroll
      for (int j=0;j<OP;j++)
        acc[i][j] = bno[j] + bk1[j] + (tg>0 ? bk0[j] : 0.f) + (tg<T_-1 ? bk2[j] : 0.f);
    }
  }

  #pragma unroll 1
  for (int cz=0; cz<NCH; ++cz){
    __syncthreads();   // protects prior-chunk reads (and sAdj/sX3 on cz==0)
    // ---- stage input chunk [SE][32]
    if (MODE == 1){
      int cg = cz*32 + (tid & 31);
      float w0 = ew[cg*3], w1 = ew[cg*3+1], w2 = ew[cg*3+2], b0 = eb[cg];
      for (int e=tid; e<SE*32; e+=256){
        int se = e>>5; int t = t0 + se/NJ - 1;
        float v = 0.f;
        if (t>=0 && t<T_) v = b0 + sX3[se*3]*w0 + sX3[se*3+1]*w1 + sX3[se*3+2]*w2;
        sIn[e] = v;
      }
    } else {
      for (int e4=tid; e4<SE*8; e4+=256){
        int se = e4>>3; int cc = (e4&7)<<2;
        int tl = se/NJ; int u = se - tl*NJ; int t = t0 + tl - 1;
        float4 v = make_float4(0.f,0.f,0.f,0.f);
        if (t>=0 && t<T_) v = *(const float4*)&in[(((size_t)b*T_ + t)*NJ + u)*(size_t)Cin + cz*32 + cc];
        *(float4*)&sIn[se*32+cc] = v;
      }
    }
    __syncthreads();
    // ---- xg chunk = adj @ in
    for (int e=tid; e<SE*32; e+=256){
      int se = e>>5; int c = e&31; int u = se%NJ; int base = (se-u)*32 + c;
      float a = 0.f;
      #pragma unroll
      for (int v=0; v<NJ; v++) a += sAdj[u*NJ+v]*sIn[base + v*32];
      sXg[e] = a;
    }
    __syncthreads();
    // ---- partial conv over this chunk (k unrolled, ds-reads batched in G)
    #pragma unroll
    for (int k=0;k<3;k++){
      const float* Wk = W + (size_t)(k*Cin + cz*32)*COS;
      #pragma unroll
      for (int c4=0;c4<32;c4+=4){
        float wv[4][OP];
        #pragma unroll
        for (int q=0;q<4;q++)
          #pragma unroll
          for (int j=0;j<OP;j++) wv[q][j] = Wk[(size_t)(c4+q)*COS + j*32 + o];
        #pragma unroll
        for (int i0=0;i0<SP;i0+=G){
          float4 xr[G];
          #pragma unroll
          for (int u=0;u<G;u++)
            xr[u] = *(const float4*)&sXg[(s0+i0+u+k*NJ)*32 + c4];
          #pragma unroll
          for (int u=0;u<G;u++)
            #pragma unroll
            for (int j=0;j<OP;j++)
              acc[i0+u][j] += xr[u].x*wv[0][j] + xr[u].y*wv[1][j] + xr[u].z*wv[2][j] + xr[u].w*wv[3][j];
        }
      }
    }
    // ---- partial residual over this chunk
    if (MODE == 1){
      float rsv = RS[cz*32 + o];     // output channel cz*32+o -> j==cz
      #pragma unroll
      for (int i0=0;i0<SP;i0+=G){
        float xr[G];
        #pragma unroll
        for (int u=0;u<G;u++) xr[u] = sIn[(s0+i0+u+NJ)*32 + o];
        #pragma unroll
        for (int u=0;u<G;u++) acc[i0+u][cz] += xr[u]*rsv;
      }
    } else {
      #pragma unroll
      for (int c4=0;c4<32;c4+=4){
        float rv[4][OP];
        #pragma unroll
        for (int q=0;q<4;q++)
          #pragma unroll
          for (int j=0;j<OP;j++) rv[q][j] = RW[(size_t)(cz*32+c4+q)*COS + j*32 + o];
        #pragma unroll
        for (int i0=0;i0<SP;i0+=G){
          float4 xr[G];
          #pragma unroll
          for (int u=0;u<G;u++)
            xr[u] = *(const float4*)&sIn[(s0+i0+u+NJ)*32 + c4];
          #pragma unroll
          for (int u=0;u<G;u++)
            #pragma unroll
            for (int j=0;j<OP;j++)
              acc[i0+u][j] += xr[u].x*rv[0][j] + xr[u].y*rv[1][j] + xr[u].z*rv[2][j] + xr[u].w*rv[3][j];
        }
      }
    }
  }
  // ---- epilogue
  if (MODE == 3){
    #pragma unroll
    for (int j=0;j<OP;j++){
      float sum = 0.f;
      #pragma unroll
      for (int i=0;i<SP;i++) sum += fmaxf(acc[i][j], 0.f);
      atomicAdd(&out[(size_t)b*64 + j*32 + o], sum);
    }
  } else {
    size_t obase = ((size_t)b*T_ + t0)*NJ*COS;
    #pragma unroll
    for (int i=0;i<SP;i++)
      #pragma unroll
      for (int j=0;j<OP;j++)
        out[obase + (size_t)(s0+i)*COS + j*32 + o] = fmaxf(acc[i][j], 0.f);
  }
}

// ---------------- VQ ---------------------------------------------------------
__global__ __launch_bounds__(128) void vq_kernel(const float* __restrict__ feat,
    const float* __restrict__ cb, float* __restrict__ dout){
  int b = blockIdx.x, g = blockIdx.y, tid = threadIdx.x;
  __shared__ float sF[64];
  __shared__ float sD[128]; __shared__ int sI[128];
  __shared__ float sL[64];
  float inv = 1.0f/(256.0f*(float)d_gn[g]);
  if (tid < 64) sF[tid] = feat[((size_t)g*64 + b)*64 + tid]*inv;
  __syncthreads();
  const float* cbg = cb + (size_t)g*128*64;
  {
    const float* c = cbg + (size_t)tid*64;
    float d = 0.f;
    for (int i=0;i<64;i++){ float df = c[i]-sF[i]; d += df*df; }
    sD[tid] = d; sI[tid] = tid;
  }
  __syncthreads();
  for (int s=64; s>0; s>>=1){
    if (tid < s){
      float d2 = sD[tid+s]; int i2 = sI[tid+s];
      if (d2 < sD[tid] || (d2 == sD[tid] && i2 < sI[tid])){ sD[tid]=d2; sI[tid]=i2; }
    }
    __syncthreads();
  }
  int idx = sI[0];
  if (tid < 64){
    float q = cbg[(size_t)idx*64 + tid];
    dout[((size_t)g*64 + b)*64 + tid] = q;
    float df = q - sF[tid];
    sL[tid] = df*df;
  }
  __syncthreads();
  if (tid == 0){
    float s = 0.f;
    for (int i=0;i<64;i++) s += sL[i];
    atomicAdd(dout + 20480, 1.25f*s/4096.0f);
    dout[20481 + g*64 + b] = (float)idx;
  }
}

// ---------------- dispatch helpers ------------------------------------------
static void launch_st1(int nj, hipStream_t s, const float* x, float* A1,
    const float* WC, const float* BV, const float* RS, const float* adj,
    const float* ew, const float* eb, int gstart){
  dim3 grid(T_/16, B_, 1);
  switch(nj){
    case 4: st_layer<64,64,4,1><<<grid,256,0,s>>>(x,A1,WC,nullptr,BV,RS,adj,ew,eb,gstart); break;
    case 5: st_layer<64,64,5,1><<<grid,256,0,s>>>(x,A1,WC,nullptr,BV,RS,adj,ew,eb,gstart); break;
    case 6: st_layer<64,64,6,1><<<grid,256,0,s>>>(x,A1,WC,nullptr,BV,RS,adj,ew,eb,gstart); break;
  }
}
static void launch_st2(int nj, hipStream_t s, const float* A1, float* A2,
    const float* WC, const float* RW, const float* BV, const float* adj){
  dim3 grid(T_/16, B_, 2);
  switch(nj){
    case 4: st_layer<64,128,4,2><<<grid,256,0,s>>>(A1,A2,WC,RW,BV,nullptr,adj,nullptr,nullptr,0); break;
    case 5: st_layer<64,128,5,2><<<grid,256,0,s>>>(A1,A2,WC,RW,BV,nullptr,adj,nullptr,nullptr,0); break;
    case 6: st_layer<64,128,6,2><<<grid,256,0,s>>>(A1,A2,WC,RW,BV,nullptr,adj,nullptr,nullptr,0); break;
  }
}
static void launch_st3(int nj, hipStream_t s, const float* A2, float* featg,
    const float* WC, const float* RW, const float* BV, const float* adj){
  dim3 grid(T_/16, B_, 1);
  switch(nj){
    case 4: st_layer<128,64,4,3><<<grid,256,0,s>>>(A2,featg,WC,RW,BV,nullptr,adj,nullptr,nullptr,0); break;
    case 5: st_layer<128,64,5,3><<<grid,256,0,s>>>(A2,featg,WC,RW,BV,nullptr,adj,nullptr,nullptr,0); break;
    case 6: st_layer<128,64,6,3><<<grid,256,0,s>>>(A2,featg,WC,RW,BV,nullptr,adj,nullptr,nullptr,0); break;
  }
}

extern "C" void kernel_launch(void* const* d_in, const int* in_sizes, int n_in,
                              void* d_out, int out_size, void* d_ws, size_t ws_size,
                              hipStream_t stream) {
  const float* x    = (const float*)d_in[0];
  const float* ew   = (const float*)d_in[1];
  const float* eb   = (const float*)d_in[2];
  const float* sw1  = (const float*)d_in[3];
  const float* sb1  = (const float*)d_in[4];
  const float* tw1  = (const float*)d_in[5];
  const float* tb1  = (const float*)d_in[6];
  const float* bg1  = (const float*)d_in[7];
  const float* bb1  = (const float*)d_in[8];
  const float* rw2  = (const float*)d_in[9];
  const float* rb2  = (const float*)d_in[10];
  const float* rg2  = (const float*)d_in[11];
  const float* rbb2 = (const float*)d_in[12];
  const float* sw2  = (const float*)d_in[13];
  const float* sb2  = (const float*)d_in[14];
  const float* tw2  = (const float*)d_in[15];
  const float* tb2  = (const float*)d_in[16];
  const float* bg2  = (const float*)d_in[17];
  const float* bb2  = (const float*)d_in[18];
  const float* rw3  = (const float*)d_in[19];
  const float* rb3  = (const float*)d_in[20];
  const float* rg3  = (const float*)d_in[21];
  const float* rbb3 = (const float*)d_in[22];
  const float* sw3  = (const float*)d_in[23];
  const float* sb3  = (const float*)d_in[24];
  const float* tw3  = (const float*)d_in[25];
  const float* tb3  = (const float*)d_in[26];
  const float* bg3  = (const float*)d_in[27];
  const float* bb3  = (const float*)d_in[28];
  const float* cbs  = (const float*)d_in[29];
  float* dout = (float*)d_out;
  float* ws = (float*)d_ws;

  const size_t OFF_ADJ = 0;
  const size_t OFF_WC1 = 256;
  const size_t OFF_B1  = 61696;
  const size_t OFF_RS1 = 62976;
  const size_t OFF_WC2 = 63296;
  const size_t OFF_RW2 = 186176;
  const size_t OFF_B2  = 227136;
  const size_t OFF_WC3 = 229696;
  const size_t OFF_RW3 = 352576;
  const size_t OFF_B3  = 393536;
  const size_t OFF_FEAT= 394816;
  const size_t OFF_A1  = 415296;
  const size_t OFF_A2  = 6706752;
  const size_t WS_FLOATS = 19289664;
  if (ws_size < WS_FLOATS*sizeof(float)) return; // insufficient workspace -> fail loudly at validation

  float* adj5 = ws + OFF_ADJ;
  float* WC1  = ws + OFF_WC1;  float* B1 = ws + OFF_B1;  float* RS1 = ws + OFF_RS1;
  float* WC2  = ws + OFF_WC2;  float* RW2 = ws + OFF_RW2; float* B2 = ws + OFF_B2;
  float* WC3  = ws + OFF_WC3;  float* RW3 = ws + OFF_RW3; float* B3 = ws + OFF_B3;
  float* feat = ws + OFF_FEAT;
  float* A1   = ws + OFF_A1;
  float* A2   = ws + OFF_A2;

  // prep-phase scratch aliased into the A2 region (dead until st2 writes it)
  float* twT1 = A2;            // 61440
  float* twT2 = A2 + 61440;    // 245760
  float* twT3 = A2 + 307200;   // 61440
  float* swe1 = A2 + 368640;   // 20480
  float* swe2 = A2 + 389120;   // 40960
  float* swe3 = A2 + 430080;   // 40960

  zero_kernel<<<80, 256, 0, stream>>>(feat, dout + 20480);
  adj_kernel<<<1, 64, 0, stream>>>(adj5);
  fold_swe<<<400, 256, 0, stream>>>(sw1, sw2, sw3, swe1, swe2, swe3);
  transpose_tw<64,64>  <<<240, 256, 0, stream>>>(tw1, twT1);
  transpose_tw<128,128><<<960, 256, 0, stream>>>(tw2, twT2);
  transpose_tw<64,64>  <<<240, 256, 0, stream>>>(tw3, twT3);
  prep_gemm<64,64,64>  <<<dim3(5,3,16), 256, 0, stream>>>(twT1, swe1, bg1, WC1);
  prep_gemm<128,64,128><<<dim3(5,3,32), 256, 0, stream>>>(twT2, swe2, bg2, WC2);
  prep_gemm<64,128,64> <<<dim3(5,3,32), 256, 0, stream>>>(twT3, swe3, bg3, WC3);
  prep_rw<<<320, 256, 0, stream>>>(rw2, rg2, bg2, rw3, rg3, bg3, RW2, RW3);
  prep_bias<<<dim3(5,3), 128, 0, stream>>>(twT1, twT2, twT3,
      sb1, tb1, bg1, bb1,
      sb2, tb2, bg2, bb2, rb2, rg2, rbb2,
      sb3, tb3, bg3, bb3, rb3, rg3, rbb3,
      B1, RS1, B2, B3);

  const int h_gn[5] = {5,6,6,4,4};
  const int h_gstart[5] = {0,5,11,17,21};
  for (int g=0; g<5; g++){
    int nj = h_gn[g];
    launch_st1(nj, stream, x, A1, WC1 + (size_t)g*12288, B1 + g*256, RS1 + g*64,
               adj5 + g*36, ew, eb, h_gstart[g]);
    launch_st2(nj, stream, A1, A2, WC2 + (size_t)g*24576, RW2 + (size_t)g*8192,
               B2 + g*512, adj5 + g*36);
    launch_st3(nj, stream, A2, feat + (size_t)g*4096, WC3 + (size_t)g*24576,
               RW3 + (size_t)g*8192, B3 + g*256, adj5 + g*36);
  }
  vq_kernel<<<dim3(B_,5), 128, 0, stream>>>(feat, cbs, dout);
}

// Round 6
// 9556.849 us; speedup vs baseline: 1.5005x; 1.4318x over previous
//
#include <hip/hip_runtime.h>

#define T_ 256
#define B_ 64
static constexpr float BNS = 0.9999950000374997f; // 1/sqrt(1+1e-5)

__device__ __constant__ int d_perm[25] = {0,1,2,3,20, 4,5,6,7,21,22, 8,9,10,11,23,24, 12,13,14,15, 16,17,18,19};
__device__ __constant__ int d_gstart[5] = {0,5,11,17,21};
__device__ __constant__ int d_gn[5] = {5,6,6,4,4};
// 0-indexed valid skeleton edges (entries (1,0),(0,12),(0,16) of the 1-indexed
// list go out of bounds after -1 and are skipped by the reference)
__device__ __constant__ int d_edges[21][2] = {
  {2,1},{1,19},{19,0},{19,3},{3,4},{4,5},{5,21},{5,6},{6,20},{19,7},
  {7,8},{8,9},{9,23},{9,10},{10,22},{11,12},{12,13},{13,14},{15,16},{16,17},{17,18}};

// ---------------- adjacency (fp64, exact reproduction of _sub_adj) -----------
__global__ void adj_kernel(float* __restrict__ adjout){ // [5][36], row stride = n (compact), zero padded
  if (threadIdx.x != 0 || blockIdx.x != 0) return;
  double fa[25][25];
  for (int i=0;i<25;i++) for (int j=0;j<25;j++) fa[i][j]=0.0;
  for (int e=0;e<21;e++){ int i=d_edges[e][0], j=d_edges[e][1]; fa[i][j]=1.0; fa[j][i]=1.0; }
  for (int i=0;i<25;i++) fa[i][i] += 1.0;
  for (int i=0;i<25;i++){
    double dg=0; for (int j=0;j<25;j++) dg += fa[i][j];
    if (dg==0.0) dg=1.0;
    for (int j=0;j<25;j++) fa[i][j] /= dg;
  }
  for (int g=0; g<5; g++){
    int n = d_gn[g]; int gs = d_gstart[g];
    for (int q=0;q<36;q++) adjout[g*36+q] = 0.f;
    double sa[6][6];
    for (int a=0;a<n;a++) for (int b=0;b<n;b++) sa[a][b] = fa[d_perm[gs+a]][d_perm[gs+b]];
    for (int a=0;a<n;a++) sa[a][a] += 1.0;            // n>1 for all groups
    double deg[6];
    for (int a=0;a<n;a++){ double s=0; for (int b=0;b<n;b++) s += sa[a][b]; deg[a]=s; }
    for (int a=1;a<n;a++) if (deg[a]==1.0){ sa[0][a]=1.0; sa[a][0]=1.0; }
    for (int a=0;a<n;a++){
      double s=0; for (int b=0;b<n;b++) s += sa[a][b];
      if (s==0.0) s=1.0;
      for (int b=0;b<n;b++) adjout[g*36 + a*n + b] = (float)(sa[a][b]/s);
    }
  }
}

__global__ void zero_kernel(float* __restrict__ feat, float* __restrict__ loss){
  int i = blockIdx.x*256 + threadIdx.x;
  if (i < 5*64*64) feat[i] = 0.f;
  if (i == 0) loss[0] = 0.f;
}

// ---------------- parallel weight prep --------------------------------------
__global__ __launch_bounds__(256) void fold_swe(
    const float* __restrict__ sw1, const float* __restrict__ sw2, const float* __restrict__ sw3,
    float* __restrict__ swe1, float* __restrict__ swe2, float* __restrict__ swe3){
  int i = blockIdx.x*256 + threadIdx.x;
  if (i < 20480){ int g=i/4096, r=i%4096;
    swe1[i] = sw1[g*12288 + r] + sw1[g*12288 + 4096 + r] + sw1[g*12288 + 8192 + r];
  } else if (i < 61440){ int j=i-20480; int g=j/8192, r=j%8192;
    swe2[j] = sw2[g*24576 + r] + sw2[g*24576 + 8192 + r] + sw2[g*24576 + 16384 + r];
  } else if (i < 102400){ int j=i-61440; int g=j/8192, r=j%8192;
    swe3[j] = sw3[g*24576 + r] + sw3[g*24576 + 8192 + r] + sw3[g*24576 + 16384 + r];
  }
}

template<int Cm, int Cout>
__global__ __launch_bounds__(256) void transpose_tw(const float* __restrict__ tw, float* __restrict__ twT){
  int e = blockIdx.x*256 + threadIdx.x;
  if (e >= 5*3*Cm*Cout) return;
  int o = e % Cout;
  int t = e / Cout;
  int m = t % Cm; t /= Cm;
  int k = t % 3; int g = t/3;
  twT[e] = tw[(size_t)g*Cout*Cm*3 + (o*Cm+m)*3 + k];
}

template<int Cm, int Cin, int Cout>
__global__ __launch_bounds__(256) void prep_gemm(
    const float* __restrict__ twT, const float* __restrict__ swe,
    const float* __restrict__ bg, float* __restrict__ WC){
  constexpr int CT = 256/Cout;
  __shared__ float sS[Cm*CT];
  int g = blockIdx.x, k = blockIdx.y, cz = blockIdx.z;
  int tid = threadIdx.x;
  for (int i=tid; i<Cm*CT; i+=256){
    int m = i/CT, cc = i%CT;
    sS[i] = swe[(size_t)g*Cm*Cin + m*Cin + cz*CT + cc];
  }
  __syncthreads();
  int o = tid % Cout, cc = tid / Cout;
  const float* tp = twT + ((size_t)(g*3+k)*Cm)*Cout + o;
  float acc = 0.f;
  #pragma unroll 4
  for (int m=0;m<Cm;m++) acc += tp[(size_t)m*Cout]*sS[m*CT+cc];
  int c = cz*CT + cc;
  WC[(size_t)g*3*Cin*Cout + ((size_t)k*Cin + c)*Cout + o] = bg[g*Cout+o]*BNS*acc;
}

__global__ __launch_bounds__(256) void prep_rw(
    const float* __restrict__ rw2, const float* __restrict__ rg2, const float* __restrict__ bg2,
    const float* __restrict__ rw3, const float* __restrict__ rg3, const float* __restrict__ bg3,
    float* __restrict__ RW2, float* __restrict__ RW3){
  int i = blockIdx.x*256 + threadIdx.x;
  if (i < 40960){ int g=i/8192, r=i%8192, c=r>>7, o=r&127;
    RW2[i] = bg2[g*128+o]*BNS*rg2[g*128+o]*BNS*rw2[(size_t)g*8192 + o*64 + c];
  } else if (i < 81920){ int j=i-40960; int g=j/8192, r=j%8192, c=r>>6, o=r&63;
    RW3[j] = bg3[g*64+o]*BNS*rg3[g*64+o]*BNS*rw3[(size_t)g*8192 + o*128 + c];
  }
}

__global__ __launch_bounds__(128) void prep_bias(
    const float* __restrict__ twT1, const float* __restrict__ twT2, const float* __restrict__ twT3,
    const float* __restrict__ sb1, const float* __restrict__ tb1, const float* __restrict__ bg1, const float* __restrict__ bb1,
    const float* __restrict__ sb2, const float* __restrict__ tb2, const float* __restrict__ bg2, const float* __restrict__ bb2,
    const float* __restrict__ rb2, const float* __restrict__ rg2, const float* __restrict__ rbb2,
    const float* __restrict__ sb3, const float* __restrict__ tb3, const float* __restrict__ bg3, const float* __restrict__ bb3,
    const float* __restrict__ rb3, const float* __restrict__ rg3, const float* __restrict__ rbb3,
    float* __restrict__ B1, float* __restrict__ RS1, float* __restrict__ B2, float* __restrict__ B3){
  __shared__ float sbe[128];
  int g = blockIdx.x, L = blockIdx.y, tid = threadIdx.x;
  if (L == 0){
    if (tid<64) sbe[tid] = sb1[g*192+tid] + sb1[g*192+64+tid] + sb1[g*192+128+tid];
    __syncthreads();
    if (tid<64){ int o=tid; float gsc = bg1[g*64+o]*BNS;
      for (int k=0;k<3;k++){ float s=0.f; const float* tp = twT1 + ((size_t)(g*3+k)*64)*64 + o;
        for (int m=0;m<64;m++) s += tp[m*64]*sbe[m];
        B1[g*256+(k+1)*64+o] = gsc*s; }
      B1[g*256+o] = gsc*tb1[g*64+o] + bb1[g*64+o];
      RS1[g*64+o] = gsc;
    }
  } else if (L == 1){
    sbe[tid] = sb2[g*384+tid] + sb2[g*384+128+tid] + sb2[g*384+256+tid];
    __syncthreads();
    { int o=tid; float gsc = bg2[g*128+o]*BNS; float rgs = rg2[g*128+o]*BNS;
      for (int k=0;k<3;k++){ float s=0.f; const float* tp = twT2 + ((size_t)(g*3+k)*128)*128 + o;
        for (int m=0;m<128;m++) s += tp[m*128]*sbe[m];
        B2[g*512+(k+1)*128+o] = gsc*s; }
      B2[g*512+o] = gsc*(tb2[g*128+o] + rgs*rb2[g*128+o] + rbb2[g*128+o]) + bb2[g*128+o];
    }
  } else {
    if (tid<64) sbe[tid] = sb3[g*192+tid] + sb3[g*192+64+tid] + sb3[g*192+128+tid];
    __syncthreads();
    if (tid<64){ int o=tid; float gsc = bg3[g*64+o]*BNS; float rgs = rg3[g*64+o]*BNS;
      for (int k=0;k<3;k++){ float s=0.f; const float* tp = twT3 + ((size_t)(g*3+k)*64)*64 + o;
        for (int m=0;m<64;m++) s += tp[m*64]*sbe[m];
        B3[g*256+(k+1)*64+o] = gsc*s; }
      B3[g*256+o] = gsc*(tb3[g*64+o] + rgs*rb3[g*64+o] + rbb3[g*64+o]) + bb3[g*64+o];
    }
  }
}

// ---------------- fused ST layer (Cin-chunked, group-batched ds reads) -------
// MODE 1: embed fused from x, identity residual (scaled), write out
// MODE 2: residual matmul RW, write out (Cout split over blockIdx.z)
// MODE 3: residual matmul RW, fused (T,V)-sum -> atomicAdd into feat
// COS = full Cout stride of W/RW/BV/out; each block computes 64 outputs.
// NOTE: plain __launch_bounds__(256) — adding a min-waves arg makes the
// allocator clamp VGPRs (44-64) and SPILL under the batched inner loop
// (R3: 44 no-spill latency-bound; R4/R5: 64 + 4 GB scratch traffic).
template<int Cin, int COS, int NJ, int MODE>
__global__ __launch_bounds__(256) void st_layer(
    const float* __restrict__ in, float* __restrict__ out,
    const float* __restrict__ W, const float* __restrict__ RW,
    const float* __restrict__ BV, const float* __restrict__ RS,
    const float* __restrict__ adjg, const float* __restrict__ ew,
    const float* __restrict__ eb, int gstart)
{
  constexpr int TC = 16;
  constexpr int SE = (TC+2)*NJ;
  constexpr int SITES = TC*NJ;
  constexpr int SP = SITES/8;
  constexpr int OP = 2;            // 64 outputs per block / 32 o-lanes
  constexpr int NCH = Cin/32;
  constexpr int G = (SP%4==0) ? 4 : 5;   // ds-read batch (bounded live range)
  __shared__ float sIn[SE*32];
  __shared__ float sXg[SE*32];
  __shared__ float sAdj[NJ*NJ];
  __shared__ float sX3[MODE==1 ? SE*3 : 1];
  const int tid = threadIdx.x;
  const int b = blockIdx.y;
  const int t0 = blockIdx.x*TC;
  const int ooff = blockIdx.z*64;
  W += ooff; BV += ooff;
  if (MODE != 1) RW += ooff;
  if (MODE == 2) out += ooff;

  if (tid < NJ*NJ) sAdj[tid] = adjg[tid];
  if (MODE == 1){
    for (int e=tid; e<SE*3; e+=256){
      int se = e/3, j = e - se*3;
      int tl = se/NJ; int u = se - tl*NJ; int t = t0 + tl - 1;
      float v = 0.f;
      if (t>=0 && t<T_){ int joint = d_perm[gstart+u]; v = in[(((size_t)b*T_ + t)*25 + joint)*3 + j]; }
      sX3[e] = v;
    }
  }

  const int lane = tid & 63;
  const int o = lane & 31;
  const int sg = (tid>>6)*2 + (lane>>5);
  const int s0 = sg*SP;

  float acc[SP][OP];
  {
    float bno[OP], bk0[OP], bk1[OP], bk2[OP];
    #pragma unroll
    for (int j=0;j<OP;j++){ int oj = j*32 + o;
      bno[j]=BV[oj]; bk0[j]=BV[COS+oj]; bk1[j]=BV[2*COS+oj]; bk2[j]=BV[3*COS+oj]; }
    #pragma unroll
    for (int i=0;i<SP;i++){
      int s = s0 + i; int tg = t0 + s/NJ;
      #pragma unroll
      for (int j=0;j<OP;j++)
        acc[i][j] = bno[j] + bk1[j] + (tg>0 ? bk0[j] : 0.f) + (tg<T_-1 ? bk2[j] : 0.f);
    }
  }

  #pragma unroll 1
  for (int cz=0; cz<NCH; ++cz){
    __syncthreads();   // protects prior-chunk reads (and sAdj/sX3 on cz==0)
    // ---- stage input chunk [SE][32]
    if (MODE == 1){
      int cg = cz*32 + (tid & 31);
      float w0 = ew[cg*3], w1 = ew[cg*3+1], w2 = ew[cg*3+2], b0 = eb[cg];
      for (int e=tid; e<SE*32; e+=256){
        int se = e>>5; int t = t0 + se/NJ - 1;
        float v = 0.f;
        if (t>=0 && t<T_) v = b0 + sX3[se*3]*w0 + sX3[se*3+1]*w1 + sX3[se*3+2]*w2;
        sIn[e] = v;
      }
    } else {
      for (int e4=tid; e4<SE*8; e4+=256){
        int se = e4>>3; int cc = (e4&7)<<2;
        int tl = se/NJ; int u = se - tl*NJ; int t = t0 + tl - 1;
        float4 v = make_float4(0.f,0.f,0.f,0.f);
        if (t>=0 && t<T_) v = *(const float4*)&in[(((size_t)b*T_ + t)*NJ + u)*(size_t)Cin + cz*32 + cc];
        *(float4*)&sIn[se*32+cc] = v;
      }
    }
    __syncthreads();
    // ---- xg chunk = adj @ in
    for (int e=tid; e<SE*32; e+=256){
      int se = e>>5; int c = e&31; int u = se%NJ; int base = (se-u)*32 + c;
      float a = 0.f;
      #pragma unroll
      for (int v=0; v<NJ; v++) a += sAdj[u*NJ+v]*sIn[base + v*32];
      sXg[e] = a;
    }
    __syncthreads();
    // ---- partial conv over this chunk (k unrolled, ds-reads batched in G)
    #pragma unroll
    for (int k=0;k<3;k++){
      const float* Wk = W + (size_t)(k*Cin + cz*32)*COS;
      #pragma unroll
      for (int c4=0;c4<32;c4+=4){
        float wv[4][OP];
        #pragma unroll
        for (int q=0;q<4;q++)
          #pragma unroll
          for (int j=0;j<OP;j++) wv[q][j] = Wk[(size_t)(c4+q)*COS + j*32 + o];
        #pragma unroll
        for (int i0=0;i0<SP;i0+=G){
          float4 xr[G];
          #pragma unroll
          for (int u=0;u<G;u++)
            xr[u] = *(const float4*)&sXg[(s0+i0+u+k*NJ)*32 + c4];
          #pragma unroll
          for (int u=0;u<G;u++)
            #pragma unroll
            for (int j=0;j<OP;j++)
              acc[i0+u][j] += xr[u].x*wv[0][j] + xr[u].y*wv[1][j] + xr[u].z*wv[2][j] + xr[u].w*wv[3][j];
        }
      }
    }
    // ---- partial residual over this chunk
    if (MODE == 1){
      // output channel cz*32+o lives in acc[.][cz]; cz is runtime (unroll 1),
      // so branch to keep the acc index compile-time constant (rule #20).
      float rsv = RS[cz*32 + o];
      if (cz == 0){
        #pragma unroll
        for (int i=0;i<SP;i++) acc[i][0] += sIn[(s0+i+NJ)*32 + o]*rsv;
      } else {
        #pragma unroll
        for (int i=0;i<SP;i++) acc[i][1] += sIn[(s0+i+NJ)*32 + o]*rsv;
      }
    } else {
      #pragma unroll
      for (int c4=0;c4<32;c4+=4){
        float rv[4][OP];
        #pragma unroll
        for (int q=0;q<4;q++)
          #pragma unroll
          for (int j=0;j<OP;j++) rv[q][j] = RW[(size_t)(cz*32+c4+q)*COS + j*32 + o];
        #pragma unroll
        for (int i0=0;i0<SP;i0+=G){
          float4 xr[G];
          #pragma unroll
          for (int u=0;u<G;u++)
            xr[u] = *(const float4*)&sIn[(s0+i0+u+NJ)*32 + c4];
          #pragma unroll
          for (int u=0;u<G;u++)
            #pragma unroll
            for (int j=0;j<OP;j++)
              acc[i0+u][j] += xr[u].x*rv[0][j] + xr[u].y*rv[1][j] + xr[u].z*rv[2][j] + xr[u].w*rv[3][j];
        }
      }
    }
  }
  // ---- epilogue
  if (MODE == 3){
    #pragma unroll
    for (int j=0;j<OP;j++){
      float sum = 0.f;
      #pragma unroll
      for (int i=0;i<SP;i++) sum += fmaxf(acc[i][j], 0.f);
      atomicAdd(&out[(size_t)b*64 + j*32 + o], sum);
    }
  } else {
    size_t obase = ((size_t)b*T_ + t0)*NJ*COS;
    #pragma unroll
    for (int i=0;i<SP;i++)
      #pragma unroll
      for (int j=0;j<OP;j++)
        out[obase + (size_t)(s0+i)*COS + j*32 + o] = fmaxf(acc[i][j], 0.f);
  }
}

// ---------------- VQ ---------------------------------------------------------
__global__ __launch_bounds__(128) void vq_kernel(const float* __restrict__ feat,
    const float* __restrict__ cb, float* __restrict__ dout){
  int b = blockIdx.x, g = blockIdx.y, tid = threadIdx.x;
  __shared__ float sF[64];
  __shared__ float sD[128]; __shared__ int sI[128];
  __shared__ float sL[64];
  float inv = 1.0f/(256.0f*(float)d_gn[g]);
  if (tid < 64) sF[tid] = feat[((size_t)g*64 + b)*64 + tid]*inv;
  __syncthreads();
  const float* cbg = cb + (size_t)g*128*64;
  {
    const float* c = cbg + (size_t)tid*64;
    float d = 0.f;
    for (int i=0;i<64;i++){ float df = c[i]-sF[i]; d += df*df; }
    sD[tid] = d; sI[tid] = tid;
  }
  __syncthreads();
  for (int s=64; s>0; s>>=1){
    if (tid < s){
      float d2 = sD[tid+s]; int i2 = sI[tid+s];
      if (d2 < sD[tid] || (d2 == sD[tid] && i2 < sI[tid])){ sD[tid]=d2; sI[tid]=i2; }
    }
    __syncthreads();
  }
  int idx = sI[0];
  if (tid < 64){
    float q = cbg[(size_t)idx*64 + tid];
    dout[((size_t)g*64 + b)*64 + tid] = q;
    float df = q - sF[tid];
    sL[tid] = df*df;
  }
  __syncthreads();
  if (tid == 0){
    float s = 0.f;
    for (int i=0;i<64;i++) s += sL[i];
    atomicAdd(dout + 20480, 1.25f*s/4096.0f);
    dout[20481 + g*64 + b] = (float)idx;
  }
}

// ---------------- dispatch helpers ------------------------------------------
static void launch_st1(int nj, hipStream_t s, const float* x, float* A1,
    const float* WC, const float* BV, const float* RS, const float* adj,
    const float* ew, const float* eb, int gstart){
  dim3 grid(T_/16, B_, 1);
  switch(nj){
    case 4: st_layer<64,64,4,1><<<grid,256,0,s>>>(x,A1,WC,nullptr,BV,RS,adj,ew,eb,gstart); break;
    case 5: st_layer<64,64,5,1><<<grid,256,0,s>>>(x,A1,WC,nullptr,BV,RS,adj,ew,eb,gstart); break;
    case 6: st_layer<64,64,6,1><<<grid,256,0,s>>>(x,A1,WC,nullptr,BV,RS,adj,ew,eb,gstart); break;
  }
}
static void launch_st2(int nj, hipStream_t s, const float* A1, float* A2,
    const float* WC, const float* RW, const float* BV, const float* adj){
  dim3 grid(T_/16, B_, 2);
  switch(nj){
    case 4: st_layer<64,128,4,2><<<grid,256,0,s>>>(A1,A2,WC,RW,BV,nullptr,adj,nullptr,nullptr,0); break;
    case 5: st_layer<64,128,5,2><<<grid,256,0,s>>>(A1,A2,WC,RW,BV,nullptr,adj,nullptr,nullptr,0); break;
    case 6: st_layer<64,128,6,2><<<grid,256,0,s>>>(A1,A2,WC,RW,BV,nullptr,adj,nullptr,nullptr,0); break;
  }
}
static void launch_st3(int nj, hipStream_t s, const float* A2, float* featg,
    const float* WC, const float* RW, const float* BV, const float* adj){
  dim3 grid(T_/16, B_, 1);
  switch(nj){
    case 4: st_layer<128,64,4,3><<<grid,256,0,s>>>(A2,featg,WC,RW,BV,nullptr,adj,nullptr,nullptr,0); break;
    case 5: st_layer<128,64,5,3><<<grid,256,0,s>>>(A2,featg,WC,RW,BV,nullptr,adj,nullptr,nullptr,0); break;
    case 6: st_layer<128,64,6,3><<<grid,256,0,s>>>(A2,featg,WC,RW,BV,nullptr,adj,nullptr,nullptr,0); break;
  }
}

extern "C" void kernel_launch(void* const* d_in, const int* in_sizes, int n_in,
                              void* d_out, int out_size, void* d_ws, size_t ws_size,
                              hipStream_t stream) {
  const float* x    = (const float*)d_in[0];
  const float* ew   = (const float*)d_in[1];
  const float* eb   = (const float*)d_in[2];
  const float* sw1  = (const float*)d_in[3];
  const float* sb1  = (const float*)d_in[4];
  const float* tw1  = (const float*)d_in[5];
  const float* tb1  = (const float*)d_in[6];
  const float* bg1  = (const float*)d_in[7];
  const float* bb1  = (const float*)d_in[8];
  const float* rw2  = (const float*)d_in[9];
  const float* rb2  = (const float*)d_in[10];
  const float* rg2  = (const float*)d_in[11];
  const float* rbb2 = (const float*)d_in[12];
  const float* sw2  = (const float*)d_in[13];
  const float* sb2  = (const float*)d_in[14];
  const float* tw2  = (const float*)d_in[15];
  const float* tb2  = (const float*)d_in[16];
  const float* bg2  = (const float*)d_in[17];
  const float* bb2  = (const float*)d_in[18];
  const float* rw3  = (const float*)d_in[19];
  const float* rb3  = (const float*)d_in[20];
  const float* rg3  = (const float*)d_in[21];
  const float* rbb3 = (const float*)d_in[22];
  const float* sw3  = (const float*)d_in[23];
  const float* sb3  = (const float*)d_in[24];
  const float* tw3  = (const float*)d_in[25];
  const float* tb3  = (const float*)d_in[26];
  const float* bg3  = (const float*)d_in[27];
  const float* bb3  = (const float*)d_in[28];
  const float* cbs  = (const float*)d_in[29];
  float* dout = (float*)d_out;
  float* ws = (float*)d_ws;

  const size_t OFF_ADJ = 0;
  const size_t OFF_WC1 = 256;
  const size_t OFF_B1  = 61696;
  const size_t OFF_RS1 = 62976;
  const size_t OFF_WC2 = 63296;
  const size_t OFF_RW2 = 186176;
  const size_t OFF_B2  = 227136;
  const size_t OFF_WC3 = 229696;
  const size_t OFF_RW3 = 352576;
  const size_t OFF_B3  = 393536;
  const size_t OFF_FEAT= 394816;
  const size_t OFF_A1  = 415296;
  const size_t OFF_A2  = 6706752;
  const size_t WS_FLOATS = 19289664;
  if (ws_size < WS_FLOATS*sizeof(float)) return; // insufficient workspace -> fail loudly at validation

  float* adj5 = ws + OFF_ADJ;
  float* WC1  = ws + OFF_WC1;  float* B1 = ws + OFF_B1;  float* RS1 = ws + OFF_RS1;
  float* WC2  = ws + OFF_WC2;  float* RW2 = ws + OFF_RW2; float* B2 = ws + OFF_B2;
  float* WC3  = ws + OFF_WC3;  float* RW3 = ws + OFF_RW3; float* B3 = ws + OFF_B3;
  float* feat = ws + OFF_FEAT;
  float* A1   = ws + OFF_A1;
  float* A2   = ws + OFF_A2;

  // prep-phase scratch aliased into the A2 region (dead until st2 writes it)
  float* twT1 = A2;            // 61440
  float* twT2 = A2 + 61440;    // 245760
  float* twT3 = A2 + 307200;   // 61440
  float* swe1 = A2 + 368640;   // 20480
  float* swe2 = A2 + 389120;   // 40960
  float* swe3 = A2 + 430080;   // 40960

  zero_kernel<<<80, 256, 0, stream>>>(feat, dout + 20480);
  adj_kernel<<<1, 64, 0, stream>>>(adj5);
  fold_swe<<<400, 256, 0, stream>>>(sw1, sw2, sw3, swe1, swe2, swe3);
  transpose_tw<64,64>  <<<240, 256, 0, stream>>>(tw1, twT1);
  transpose_tw<128,128><<<960, 256, 0, stream>>>(tw2, twT2);
  transpose_tw<64,64>  <<<240, 256, 0, stream>>>(tw3, twT3);
  prep_gemm<64,64,64>  <<<dim3(5,3,16), 256, 0, stream>>>(twT1, swe1, bg1, WC1);
  prep_gemm<128,64,128><<<dim3(5,3,32), 256, 0, stream>>>(twT2, swe2, bg2, WC2);
  prep_gemm<64,128,64> <<<dim3(5,3,32), 256, 0, stream>>>(twT3, swe3, bg3, WC3);
  prep_rw<<<320, 256, 0, stream>>>(rw2, rg2, bg2, rw3, rg3, bg3, RW2, RW3);
  prep_bias<<<dim3(5,3), 128, 0, stream>>>(twT1, twT2, twT3,
      sb1, tb1, bg1, bb1,
      sb2, tb2, bg2, bb2, rb2, rg2, rbb2,
      sb3, tb3, bg3, bb3, rb3, rg3, rbb3,
      B1, RS1, B2, B3);

  const int h_gn[5] = {5,6,6,4,4};
  const int h_gstart[5] = {0,5,11,17,21};
  for (int g=0; g<5; g++){
    int nj = h_gn[g];
    launch_st1(nj, stream, x, A1, WC1 + (size_t)g*12288, B1 + g*256, RS1 + g*64,
               adj5 + g*36, ew, eb, h_gstart[g]);
    launch_st2(nj, stream, A1, A2, WC2 + (size_t)g*24576, RW2 + (size_t)g*8192,
               B2 + g*512, adj5 + g*36);
    launch_st3(nj, stream, A2, feat + (size_t)g*4096, WC3 + (size_t)g*24576,
               RW3 + (size_t)g*8192, B3 + g*256, adj5 + g*36);
  }
  vq_kernel<<<dim3(B_,5), 128, 0, stream>>>(feat, cbs, dout);
}

// Round 7
// 1660.407 us; speedup vs baseline: 8.6363x; 5.7557x over previous
//
#include <hip/hip_runtime.h>

#define T_ 256
#define B_ 64
static constexpr float BNS = 0.9999950000374997f; // 1/sqrt(1+1e-5)

__device__ __constant__ int d_perm[25] = {0,1,2,3,20, 4,5,6,7,21,22, 8,9,10,11,23,24, 12,13,14,15, 16,17,18,19};
__device__ __constant__ int d_gstart[5] = {0,5,11,17,21};
__device__ __constant__ int d_gn[5] = {5,6,6,4,4};
// 0-indexed valid skeleton edges (entries (1,0),(0,12),(0,16) of the 1-indexed
// list go out of bounds after -1 and are skipped by the reference)
__device__ __constant__ int d_edges[21][2] = {
  {2,1},{1,19},{19,0},{19,3},{3,4},{4,5},{5,21},{5,6},{6,20},{19,7},
  {7,8},{8,9},{9,23},{9,10},{10,22},{11,12},{12,13},{13,14},{15,16},{16,17},{17,18}};

// ---------------- adjacency (fp64, exact reproduction of _sub_adj) -----------
__global__ void adj_kernel(float* __restrict__ adjout){ // [5][36], row stride = n (compact), zero padded
  if (threadIdx.x != 0 || blockIdx.x != 0) return;
  double fa[25][25];
  for (int i=0;i<25;i++) for (int j=0;j<25;j++) fa[i][j]=0.0;
  for (int e=0;e<21;e++){ int i=d_edges[e][0], j=d_edges[e][1]; fa[i][j]=1.0; fa[j][i]=1.0; }
  for (int i=0;i<25;i++) fa[i][i] += 1.0;
  for (int i=0;i<25;i++){
    double dg=0; for (int j=0;j<25;j++) dg += fa[i][j];
    if (dg==0.0) dg=1.0;
    for (int j=0;j<25;j++) fa[i][j] /= dg;
  }
  for (int g=0; g<5; g++){
    int n = d_gn[g]; int gs = d_gstart[g];
    for (int q=0;q<36;q++) adjout[g*36+q] = 0.f;
    double sa[6][6];
    for (int a=0;a<n;a++) for (int b=0;b<n;b++) sa[a][b] = fa[d_perm[gs+a]][d_perm[gs+b]];
    for (int a=0;a<n;a++) sa[a][a] += 1.0;            // n>1 for all groups
    double deg[6];
    for (int a=0;a<n;a++){ double s=0; for (int b=0;b<n;b++) s += sa[a][b]; deg[a]=s; }
    for (int a=1;a<n;a++) if (deg[a]==1.0){ sa[0][a]=1.0; sa[a][0]=1.0; }
    for (int a=0;a<n;a++){
      double s=0; for (int b=0;b<n;b++) s += sa[a][b];
      if (s==0.0) s=1.0;
      for (int b=0;b<n;b++) adjout[g*36 + a*n + b] = (float)(sa[a][b]/s);
    }
  }
}

__global__ void zero_kernel(float* __restrict__ feat, float* __restrict__ loss){
  int i = blockIdx.x*256 + threadIdx.x;
  if (i < 5*64*64) feat[i] = 0.f;
  if (i == 0) loss[0] = 0.f;
}

// ---------------- parallel weight prep --------------------------------------
__global__ __launch_bounds__(256) void fold_swe(
    const float* __restrict__ sw1, const float* __restrict__ sw2, const float* __restrict__ sw3,
    float* __restrict__ swe1, float* __restrict__ swe2, float* __restrict__ swe3){
  int i = blockIdx.x*256 + threadIdx.x;
  if (i < 20480){ int g=i/4096, r=i%4096;
    swe1[i] = sw1[g*12288 + r] + sw1[g*12288 + 4096 + r] + sw1[g*12288 + 8192 + r];
  } else if (i < 61440){ int j=i-20480; int g=j/8192, r=j%8192;
    swe2[j] = sw2[g*24576 + r] + sw2[g*24576 + 8192 + r] + sw2[g*24576 + 16384 + r];
  } else if (i < 102400){ int j=i-61440; int g=j/8192, r=j%8192;
    swe3[j] = sw3[g*24576 + r] + sw3[g*24576 + 8192 + r] + sw3[g*24576 + 16384 + r];
  }
}

template<int Cm, int Cout>
__global__ __launch_bounds__(256) void transpose_tw(const float* __restrict__ tw, float* __restrict__ twT){
  int e = blockIdx.x*256 + threadIdx.x;
  if (e >= 5*3*Cm*Cout) return;
  int o = e % Cout;
  int t = e / Cout;
  int m = t % Cm; t /= Cm;
  int k = t % 3; int g = t/3;
  twT[e] = tw[(size_t)g*Cout*Cm*3 + (o*Cm+m)*3 + k];
}

template<int Cm, int Cin, int Cout>
__global__ __launch_bounds__(256) void prep_gemm(
    const float* __restrict__ twT, const float* __restrict__ swe,
    const float* __restrict__ bg, float* __restrict__ WC){
  constexpr int CT = 256/Cout;
  __shared__ float sS[Cm*CT];
  int g = blockIdx.x, k = blockIdx.y, cz = blockIdx.z;
  int tid = threadIdx.x;
  for (int i=tid; i<Cm*CT; i+=256){
    int m = i/CT, cc = i%CT;
    sS[i] = swe[(size_t)g*Cm*Cin + m*Cin + cz*CT + cc];
  }
  __syncthreads();
  int o = tid % Cout, cc = tid / Cout;
  const float* tp = twT + ((size_t)(g*3+k)*Cm)*Cout + o;
  float acc = 0.f;
  #pragma unroll 4
  for (int m=0;m<Cm;m++) acc += tp[(size_t)m*Cout]*sS[m*CT+cc];
  int c = cz*CT + cc;
  WC[(size_t)g*3*Cin*Cout + ((size_t)k*Cin + c)*Cout + o] = bg[g*Cout+o]*BNS*acc;
}

__global__ __launch_bounds__(256) void prep_rw(
    const float* __restrict__ rw2, const float* __restrict__ rg2, const float* __restrict__ bg2,
    const float* __restrict__ rw3, const float* __restrict__ rg3, const float* __restrict__ bg3,
    float* __restrict__ RW2, float* __restrict__ RW3){
  int i = blockIdx.x*256 + threadIdx.x;
  if (i < 40960){ int g=i/8192, r=i%8192, c=r>>7, o=r&127;
    RW2[i] = bg2[g*128+o]*BNS*rg2[g*128+o]*BNS*rw2[(size_t)g*8192 + o*64 + c];
  } else if (i < 81920){ int j=i-40960; int g=j/8192, r=j%8192, c=r>>6, o=r&63;
    RW3[j] = bg3[g*64+o]*BNS*rg3[g*64+o]*BNS*rw3[(size_t)g*8192 + o*128 + c];
  }
}

__global__ __launch_bounds__(128) void prep_bias(
    const float* __restrict__ twT1, const float* __restrict__ twT2, const float* __restrict__ twT3,
    const float* __restrict__ sb1, const float* __restrict__ tb1, const float* __restrict__ bg1, const float* __restrict__ bb1,
    const float* __restrict__ sb2, const float* __restrict__ tb2, const float* __restrict__ bg2, const float* __restrict__ bb2,
    const float* __restrict__ rb2, const float* __restrict__ rg2, const float* __restrict__ rbb2,
    const float* __restrict__ sb3, const float* __restrict__ tb3, const float* __restrict__ bg3, const float* __restrict__ bb3,
    const float* __restrict__ rb3, const float* __restrict__ rg3, const float* __restrict__ rbb3,
    float* __restrict__ B1, float* __restrict__ RS1, float* __restrict__ B2, float* __restrict__ B3){
  __shared__ float sbe[128];
  int g = blockIdx.x, L = blockIdx.y, tid = threadIdx.x;
  if (L == 0){
    if (tid<64) sbe[tid] = sb1[g*192+tid] + sb1[g*192+64+tid] + sb1[g*192+128+tid];
    __syncthreads();
    if (tid<64){ int o=tid; float gsc = bg1[g*64+o]*BNS;
      for (int k=0;k<3;k++){ float s=0.f; const float* tp = twT1 + ((size_t)(g*3+k)*64)*64 + o;
        for (int m=0;m<64;m++) s += tp[m*64]*sbe[m];
        B1[g*256+(k+1)*64+o] = gsc*s; }
      B1[g*256+o] = gsc*tb1[g*64+o] + bb1[g*64+o];
      RS1[g*64+o] = gsc;
    }
  } else if (L == 1){
    sbe[tid] = sb2[g*384+tid] + sb2[g*384+128+tid] + sb2[g*384+256+tid];
    __syncthreads();
    { int o=tid; float gsc = bg2[g*128+o]*BNS; float rgs = rg2[g*128+o]*BNS;
      for (int k=0;k<3;k++){ float s=0.f; const float* tp = twT2 + ((size_t)(g*3+k)*128)*128 + o;
        for (int m=0;m<128;m++) s += tp[m*128]*sbe[m];
        B2[g*512+(k+1)*128+o] = gsc*s; }
      B2[g*512+o] = gsc*(tb2[g*128+o] + rgs*rb2[g*128+o] + rbb2[g*128+o]) + bb2[g*128+o];
    }
  } else {
    if (tid<64) sbe[tid] = sb3[g*192+tid] + sb3[g*192+64+tid] + sb3[g*192+128+tid];
    __syncthreads();
    if (tid<64){ int o=tid; float gsc = bg3[g*64+o]*BNS; float rgs = rg3[g*64+o]*BNS;
      for (int k=0;k<3;k++){ float s=0.f; const float* tp = twT3 + ((size_t)(g*3+k)*64)*64 + o;
        for (int m=0;m<64;m++) s += tp[m*64]*sbe[m];
        B3[g*256+(k+1)*64+o] = gsc*s; }
      B3[g*256+o] = gsc*(tb3[g*64+o] + rgs*rb3[g*64+o] + rbb3[g*64+o]) + bb3[g*64+o];
    }
  }
}

// ---------------- fused ST layer (Cin-chunked, OP=4 wide output tile) --------
// MODE 1: embed fused from x, identity residual (scaled), write out
// MODE 2: residual matmul RW, write out (Cout split over blockIdx.z)
// MODE 3: residual matmul RW, fused (T,V)-sum -> atomicAdd into feat
// COS = full Cout stride of W/RW/BV/out; each block computes 64 outputs.
// Layout: o = lane&15 (16 o-lanes), OP=4 outputs/thread, 16 site-groups.
// Each ds_read_b128 feeds 16 FMAs (vs 8 at OP=2) -> half the LDS traffic.
// LDS row stride RST=36 floats (144B): rows land on distinct banks for the
// wave's 4 concurrent row addresses (SP*36 mod 32 = 24/20/16) -> <=2-way.
// Loop shape kept EXACTLY as R3 (k unroll 1, c4 unroll 2, no manual batching):
// aggressive unroll/batching makes the scheduler hoist whole read batches and
// spill catastrophically even at 256 VGPRs (R4-R6).
template<int Cin, int COS, int NJ, int MODE>
__global__ __launch_bounds__(256) void st_layer(
    const float* __restrict__ in, float* __restrict__ out,
    const float* __restrict__ W, const float* __restrict__ RW,
    const float* __restrict__ BV, const float* __restrict__ RS,
    const float* __restrict__ adjg, const float* __restrict__ ew,
    const float* __restrict__ eb, int gstart)
{
  constexpr int TC = 16;
  constexpr int SE = (TC+2)*NJ;
  constexpr int SITES = TC*NJ;
  constexpr int SP = SITES/16;     // sites per thread (6/5/4)
  constexpr int OP = 4;            // outputs per thread (x 16 lanes = 64)
  constexpr int NCH = Cin/32;
  constexpr int RST = 36;          // LDS row stride (floats), 16B-aligned, anti-conflict
  __shared__ float sIn[SE*RST];
  __shared__ float sXg[SE*RST];
  __shared__ float sAdj[NJ*NJ];
  __shared__ float sX3[MODE==1 ? SE*3 : 1];
  const int tid = threadIdx.x;
  const int b = blockIdx.y;
  const int t0 = blockIdx.x*TC;
  const int ooff = blockIdx.z*64;
  W += ooff; BV += ooff;
  if (MODE != 1) RW += ooff;
  if (MODE == 2) out += ooff;

  if (tid < NJ*NJ) sAdj[tid] = adjg[tid];
  if (MODE == 1){
    for (int e=tid; e<SE*3; e+=256){
      int se = e/3, j = e - se*3;
      int tl = se/NJ; int u = se - tl*NJ; int t = t0 + tl - 1;
      float v = 0.f;
      if (t>=0 && t<T_){ int joint = d_perm[gstart+u]; v = in[(((size_t)b*T_ + t)*25 + joint)*3 + j]; }
      sX3[e] = v;
    }
  }

  const int o = tid & 15;          // o-lane
  const int sg = tid >> 4;         // site group 0..15
  const int s0 = sg*SP;

  float acc[SP][OP];
  {
    float bno[OP], bk0[OP], bk1[OP], bk2[OP];
    #pragma unroll
    for (int j=0;j<OP;j++){ int oj = j*16 + o;
      bno[j]=BV[oj]; bk0[j]=BV[COS+oj]; bk1[j]=BV[2*COS+oj]; bk2[j]=BV[3*COS+oj]; }
    #pragma unroll
    for (int i=0;i<SP;i++){
      int s = s0 + i; int tg = t0 + s/NJ;
      #pragma unroll
      for (int j=0;j<OP;j++)
        acc[i][j] = bno[j] + bk1[j] + (tg>0 ? bk0[j] : 0.f) + (tg<T_-1 ? bk2[j] : 0.f);
    }
  }

  #pragma unroll 1
  for (int cz=0; cz<NCH; ++cz){
    __syncthreads();   // protects prior-chunk reads (and sAdj/sX3 on cz==0)
    // ---- stage input chunk [SE][32] (row stride RST)
    if (MODE == 1){
      int cg = cz*32 + (tid & 31);
      float w0 = ew[cg*3], w1 = ew[cg*3+1], w2 = ew[cg*3+2], b0 = eb[cg];
      for (int e=tid; e<SE*32; e+=256){
        int se = e>>5; int c = e&31; int t = t0 + se/NJ - 1;
        float v = 0.f;
        if (t>=0 && t<T_) v = b0 + sX3[se*3]*w0 + sX3[se*3+1]*w1 + sX3[se*3+2]*w2;
        sIn[se*RST + c] = v;
      }
    } else {
      for (int e4=tid; e4<SE*8; e4+=256){
        int se = e4>>3; int cc = (e4&7)<<2;
        int tl = se/NJ; int u = se - tl*NJ; int t = t0 + tl - 1;
        float4 v = make_float4(0.f,0.f,0.f,0.f);
        if (t>=0 && t<T_) v = *(const float4*)&in[(((size_t)b*T_ + t)*NJ + u)*(size_t)Cin + cz*32 + cc];
        *(float4*)&sIn[se*RST+cc] = v;
      }
    }
    __syncthreads();
    // ---- xg chunk = adj @ in
    for (int e=tid; e<SE*32; e+=256){
      int se = e>>5; int c = e&31; int u = se%NJ; int base = (se-u)*RST + c;
      float a = 0.f;
      #pragma unroll
      for (int v=0; v<NJ; v++) a += sAdj[u*NJ+v]*sIn[base + v*RST];
      sXg[se*RST + c] = a;
    }
    __syncthreads();
    // ---- partial conv over this chunk
    #pragma unroll 1
    for (int k=0;k<3;k++){
      const float* Wk = W + (size_t)(k*Cin + cz*32)*COS;
      #pragma unroll 2
      for (int c4=0;c4<32;c4+=4){
        float wv[4][OP];
        #pragma unroll
        for (int q=0;q<4;q++)
          #pragma unroll
          for (int j=0;j<OP;j++) wv[q][j] = Wk[(size_t)(c4+q)*COS + j*16 + o];
        #pragma unroll
        for (int i=0;i<SP;i++){
          const float4 xv = *(const float4*)&sXg[(s0+i+k*NJ)*RST + c4];
          #pragma unroll
          for (int j=0;j<OP;j++)
            acc[i][j] += xv.x*wv[0][j] + xv.y*wv[1][j] + xv.z*wv[2][j] + xv.w*wv[3][j];
        }
      }
    }
    // ---- partial residual over this chunk
    if (MODE == 1){
      // channel j*16+o is in chunk cz iff j in {2cz, 2cz+1}; static indices.
      if (cz == 0){
        float r0 = RS[o], r1 = RS[16+o];
        #pragma unroll
        for (int i=0;i<SP;i++){
          acc[i][0] += sIn[(s0+i+NJ)*RST + o]*r0;
          acc[i][1] += sIn[(s0+i+NJ)*RST + 16 + o]*r1;
        }
      } else {
        float r2 = RS[32+o], r3 = RS[48+o];
        #pragma unroll
        for (int i=0;i<SP;i++){
          acc[i][2] += sIn[(s0+i+NJ)*RST + o]*r2;
          acc[i][3] += sIn[(s0+i+NJ)*RST + 16 + o]*r3;
        }
      }
    } else {
      #pragma unroll 2
      for (int c4=0;c4<32;c4+=4){
        float rv[4][OP];
        #pragma unroll
        for (int q=0;q<4;q++)
          #pragma unroll
          for (int j=0;j<OP;j++) rv[q][j] = RW[(size_t)(cz*32+c4+q)*COS + j*16 + o];
        #pragma unroll
        for (int i=0;i<SP;i++){
          const float4 xv = *(const float4*)&sIn[(s0+i+NJ)*RST + c4];
          #pragma unroll
          for (int j=0;j<OP;j++)
            acc[i][j] += xv.x*rv[0][j] + xv.y*rv[1][j] + xv.z*rv[2][j] + xv.w*rv[3][j];
        }
      }
    }
  }
  // ---- epilogue
  if (MODE == 3){
    #pragma unroll
    for (int j=0;j<OP;j++){
      float sum = 0.f;
      #pragma unroll
      for (int i=0;i<SP;i++) sum += fmaxf(acc[i][j], 0.f);
      atomicAdd(&out[(size_t)b*64 + j*16 + o], sum);
    }
  } else {
    size_t obase = ((size_t)b*T_ + t0)*NJ*COS;
    #pragma unroll
    for (int i=0;i<SP;i++)
      #pragma unroll
      for (int j=0;j<OP;j++)
        out[obase + (size_t)(s0+i)*COS + j*16 + o] = fmaxf(acc[i][j], 0.f);
  }
}

// ---------------- VQ ---------------------------------------------------------
__global__ __launch_bounds__(128) void vq_kernel(const float* __restrict__ feat,
    const float* __restrict__ cb, float* __restrict__ dout){
  int b = blockIdx.x, g = blockIdx.y, tid = threadIdx.x;
  __shared__ float sF[64];
  __shared__ float sD[128]; __shared__ int sI[128];
  __shared__ float sL[64];
  float inv = 1.0f/(256.0f*(float)d_gn[g]);
  if (tid < 64) sF[tid] = feat[((size_t)g*64 + b)*64 + tid]*inv;
  __syncthreads();
  const float* cbg = cb + (size_t)g*128*64;
  {
    const float* c = cbg + (size_t)tid*64;
    float d = 0.f;
    for (int i=0;i<64;i++){ float df = c[i]-sF[i]; d += df*df; }
    sD[tid] = d; sI[tid] = tid;
  }
  __syncthreads();
  for (int s=64; s>0; s>>=1){
    if (tid < s){
      float d2 = sD[tid+s]; int i2 = sI[tid+s];
      if (d2 < sD[tid] || (d2 == sD[tid] && i2 < sI[tid])){ sD[tid]=d2; sI[tid]=i2; }
    }
    __syncthreads();
  }
  int idx = sI[0];
  if (tid < 64){
    float q = cbg[(size_t)idx*64 + tid];
    dout[((size_t)g*64 + b)*64 + tid] = q;
    float df = q - sF[tid];
    sL[tid] = df*df;
  }
  __syncthreads();
  if (tid == 0){
    float s = 0.f;
    for (int i=0;i<64;i++) s += sL[i];
    atomicAdd(dout + 20480, 1.25f*s/4096.0f);
    dout[20481 + g*64 + b] = (float)idx;
  }
}

// ---------------- dispatch helpers ------------------------------------------
static void launch_st1(int nj, hipStream_t s, const float* x, float* A1,
    const float* WC, const float* BV, const float* RS, const float* adj,
    const float* ew, const float* eb, int gstart){
  dim3 grid(T_/16, B_, 1);
  switch(nj){
    case 4: st_layer<64,64,4,1><<<grid,256,0,s>>>(x,A1,WC,nullptr,BV,RS,adj,ew,eb,gstart); break;
    case 5: st_layer<64,64,5,1><<<grid,256,0,s>>>(x,A1,WC,nullptr,BV,RS,adj,ew,eb,gstart); break;
    case 6: st_layer<64,64,6,1><<<grid,256,0,s>>>(x,A1,WC,nullptr,BV,RS,adj,ew,eb,gstart); break;
  }
}
static void launch_st2(int nj, hipStream_t s, const float* A1, float* A2,
    const float* WC, const float* RW, const float* BV, const float* adj){
  dim3 grid(T_/16, B_, 2);
  switch(nj){
    case 4: st_layer<64,128,4,2><<<grid,256,0,s>>>(A1,A2,WC,RW,BV,nullptr,adj,nullptr,nullptr,0); break;
    case 5: st_layer<64,128,5,2><<<grid,256,0,s>>>(A1,A2,WC,RW,BV,nullptr,adj,nullptr,nullptr,0); break;
    case 6: st_layer<64,128,6,2><<<grid,256,0,s>>>(A1,A2,WC,RW,BV,nullptr,adj,nullptr,nullptr,0); break;
  }
}
static void launch_st3(int nj, hipStream_t s, const float* A2, float* featg,
    const float* WC, const float* RW, const float* BV, const float* adj){
  dim3 grid(T_/16, B_, 1);
  switch(nj){
    case 4: st_layer<128,64,4,3><<<grid,256,0,s>>>(A2,featg,WC,RW,BV,nullptr,adj,nullptr,nullptr,0); break;
    case 5: st_layer<128,64,5,3><<<grid,256,0,s>>>(A2,featg,WC,RW,BV,nullptr,adj,nullptr,nullptr,0); break;
    case 6: st_layer<128,64,6,3><<<grid,256,0,s>>>(A2,featg,WC,RW,BV,nullptr,adj,nullptr,nullptr,0); break;
  }
}

extern "C" void kernel_launch(void* const* d_in, const int* in_sizes, int n_in,
                              void* d_out, int out_size, void* d_ws, size_t ws_size,
                              hipStream_t stream) {
  const float* x    = (const float*)d_in[0];
  const float* ew   = (const float*)d_in[1];
  const float* eb   = (const float*)d_in[2];
  const float* sw1  = (const float*)d_in[3];
  const float* sb1  = (const float*)d_in[4];
  const float* tw1  = (const float*)d_in[5];
  const float* tb1  = (const float*)d_in[6];
  const float* bg1  = (const float*)d_in[7];
  const float* bb1  = (const float*)d_in[8];
  const float* rw2  = (const float*)d_in[9];
  const float* rb2  = (const float*)d_in[10];
  const float* rg2  = (const float*)d_in[11];
  const float* rbb2 = (const float*)d_in[12];
  const float* sw2  = (const float*)d_in[13];
  const float* sb2  = (const float*)d_in[14];
  const float* tw2  = (const float*)d_in[15];
  const float* tb2  = (const float*)d_in[16];
  const float* bg2  = (const float*)d_in[17];
  const float* bb2  = (const float*)d_in[18];
  const float* rw3  = (const float*)d_in[19];
  const float* rb3  = (const float*)d_in[20];
  const float* rg3  = (const float*)d_in[21];
  const float* rbb3 = (const float*)d_in[22];
  const float* sw3  = (const float*)d_in[23];
  const float* sb3  = (const float*)d_in[24];
  const float* tw3  = (const float*)d_in[25];
  const float* tb3  = (const float*)d_in[26];
  const float* bg3  = (const float*)d_in[27];
  const float* bb3  = (const float*)d_in[28];
  const float* cbs  = (const float*)d_in[29];
  float* dout = (float*)d_out;
  float* ws = (float*)d_ws;

  const size_t OFF_ADJ = 0;
  const size_t OFF_WC1 = 256;
  const size_t OFF_B1  = 61696;
  const size_t OFF_RS1 = 62976;
  const size_t OFF_WC2 = 63296;
  const size_t OFF_RW2 = 186176;
  const size_t OFF_B2  = 227136;
  const size_t OFF_WC3 = 229696;
  const size_t OFF_RW3 = 352576;
  const size_t OFF_B3  = 393536;
  const size_t OFF_FEAT= 394816;
  const size_t OFF_A1  = 415296;
  const size_t OFF_A2  = 6706752;
  const size_t WS_FLOATS = 19289664;
  if (ws_size < WS_FLOATS*sizeof(float)) return; // insufficient workspace -> fail loudly at validation

  float* adj5 = ws + OFF_ADJ;
  float* WC1  = ws + OFF_WC1;  float* B1 = ws + OFF_B1;  float* RS1 = ws + OFF_RS1;
  float* WC2  = ws + OFF_WC2;  float* RW2 = ws + OFF_RW2; float* B2 = ws + OFF_B2;
  float* WC3  = ws + OFF_WC3;  float* RW3 = ws + OFF_RW3; float* B3 = ws + OFF_B3;
  float* feat = ws + OFF_FEAT;
  float* A1   = ws + OFF_A1;
  float* A2   = ws + OFF_A2;

  // prep-phase scratch aliased into the A2 region (dead until st2 writes it)
  float* twT1 = A2;            // 61440
  float* twT2 = A2 + 61440;    // 245760
  float* twT3 = A2 + 307200;   // 61440
  float* swe1 = A2 + 368640;   // 20480
  float* swe2 = A2 + 389120;   // 40960
  float* swe3 = A2 + 430080;   // 40960

  zero_kernel<<<80, 256, 0, stream>>>(feat, dout + 20480);
  adj_kernel<<<1, 64, 0, stream>>>(adj5);
  fold_swe<<<400, 256, 0, stream>>>(sw1, sw2, sw3, swe1, swe2, swe3);
  transpose_tw<64,64>  <<<240, 256, 0, stream>>>(tw1, twT1);
  transpose_tw<128,128><<<960, 256, 0, stream>>>(tw2, twT2);
  transpose_tw<64,64>  <<<240, 256, 0, stream>>>(tw3, twT3);
  prep_gemm<64,64,64>  <<<dim3(5,3,16), 256, 0, stream>>>(twT1, swe1, bg1, WC1);
  prep_gemm<128,64,128><<<dim3(5,3,32), 256, 0, stream>>>(twT2, swe2, bg2, WC2);
  prep_gemm<64,128,64> <<<dim3(5,3,32), 256, 0, stream>>>(twT3, swe3, bg3, WC3);
  prep_rw<<<320, 256, 0, stream>>>(rw2, rg2, bg2, rw3, rg3, bg3, RW2, RW3);
  prep_bias<<<dim3(5,3), 128, 0, stream>>>(twT1, twT2, twT3,
      sb1, tb1, bg1, bb1,
      sb2, tb2, bg2, bb2, rb2, rg2, rbb2,
      sb3, tb3, bg3, bb3, rb3, rg3, rbb3,
      B1, RS1, B2, B3);

  const int h_gn[5] = {5,6,6,4,4};
  const int h_gstart[5] = {0,5,11,17,21};
  for (int g=0; g<5; g++){
    int nj = h_gn[g];
    launch_st1(nj, stream, x, A1, WC1 + (size_t)g*12288, B1 + g*256, RS1 + g*64,
               adj5 + g*36, ew, eb, h_gstart[g]);
    launch_st2(nj, stream, A1, A2, WC2 + (size_t)g*24576, RW2 + (size_t)g*8192,
               B2 + g*512, adj5 + g*36);
    launch_st3(nj, stream, A2, feat + (size_t)g*4096, WC3 + (size_t)g*24576,
               RW3 + (size_t)g*8192, B3 + g*256, adj5 + g*36);
  }
  vq_kernel<<<dim3(B_,5), 128, 0, stream>>>(feat, cbs, dout);
}

// Round 9
// 1606.508 us; speedup vs baseline: 8.9261x; 1.0336x over previous
//
#include <hip/hip_runtime.h>

#define T_ 256
#define B_ 64
static constexpr float BNS = 0.9999950000374997f; // 1/sqrt(1+1e-5)

__device__ __constant__ int d_perm[25] = {0,1,2,3,20, 4,5,6,7,21,22, 8,9,10,11,23,24, 12,13,14,15, 16,17,18,19};
__device__ __constant__ int d_gstart[5] = {0,5,11,17,21};
__device__ __constant__ int d_gn[5] = {5,6,6,4,4};
// 0-indexed valid skeleton edges (entries (1,0),(0,12),(0,16) of the 1-indexed
// list go out of bounds after -1 and are skipped by the reference)
__device__ __constant__ int d_edges[21][2] = {
  {2,1},{1,19},{19,0},{19,3},{3,4},{4,5},{5,21},{5,6},{6,20},{19,7},
  {7,8},{8,9},{9,23},{9,10},{10,22},{11,12},{12,13},{13,14},{15,16},{16,17},{17,18}};

// ---------------- adjacency (fp64, exact reproduction of _sub_adj) -----------
__global__ void adj_kernel(float* __restrict__ adjout){ // [5][36], row stride = n (compact), zero padded
  if (threadIdx.x != 0 || blockIdx.x != 0) return;
  double fa[25][25];
  for (int i=0;i<25;i++) for (int j=0;j<25;j++) fa[i][j]=0.0;
  for (int e=0;e<21;e++){ int i=d_edges[e][0], j=d_edges[e][1]; fa[i][j]=1.0; fa[j][i]=1.0; }
  for (int i=0;i<25;i++) fa[i][i] += 1.0;
  for (int i=0;i<25;i++){
    double dg=0; for (int j=0;j<25;j++) dg += fa[i][j];
    if (dg==0.0) dg=1.0;
    for (int j=0;j<25;j++) fa[i][j] /= dg;
  }
  for (int g=0; g<5; g++){
    int n = d_gn[g]; int gs = d_gstart[g];
    for (int q=0;q<36;q++) adjout[g*36+q] = 0.f;
    double sa[6][6];
    for (int a=0;a<n;a++) for (int b=0;b<n;b++) sa[a][b] = fa[d_perm[gs+a]][d_perm[gs+b]];
    for (int a=0;a<n;a++) sa[a][a] += 1.0;            // n>1 for all groups
    double deg[6];
    for (int a=0;a<n;a++){ double s=0; for (int b=0;b<n;b++) s += sa[a][b]; deg[a]=s; }
    for (int a=1;a<n;a++) if (deg[a]==1.0){ sa[0][a]=1.0; sa[a][0]=1.0; }
    for (int a=0;a<n;a++){
      double s=0; for (int b=0;b<n;b++) s += sa[a][b];
      if (s==0.0) s=1.0;
      for (int b=0;b<n;b++) adjout[g*36 + a*n + b] = (float)(sa[a][b]/s);
    }
  }
}

__global__ void zero_kernel(float* __restrict__ feat, float* __restrict__ loss){
  int i = blockIdx.x*256 + threadIdx.x;
  if (i < 5*64*64) feat[i] = 0.f;
  if (i == 0) loss[0] = 0.f;
}

// ---------------- parallel weight prep --------------------------------------
__global__ __launch_bounds__(256) void fold_swe(
    const float* __restrict__ sw1, const float* __restrict__ sw2, const float* __restrict__ sw3,
    float* __restrict__ swe1, float* __restrict__ swe2, float* __restrict__ swe3){
  int i = blockIdx.x*256 + threadIdx.x;
  if (i < 20480){ int g=i/4096, r=i%4096;
    swe1[i] = sw1[g*12288 + r] + sw1[g*12288 + 4096 + r] + sw1[g*12288 + 8192 + r];
  } else if (i < 61440){ int j=i-20480; int g=j/8192, r=j%8192;
    swe2[j] = sw2[g*24576 + r] + sw2[g*24576 + 8192 + r] + sw2[g*24576 + 16384 + r];
  } else if (i < 102400){ int j=i-61440; int g=j/8192, r=j%8192;
    swe3[j] = sw3[g*24576 + r] + sw3[g*24576 + 8192 + r] + sw3[g*24576 + 16384 + r];
  }
}

template<int Cm, int Cout>
__global__ __launch_bounds__(256) void transpose_tw(const float* __restrict__ tw, float* __restrict__ twT){
  int e = blockIdx.x*256 + threadIdx.x;
  if (e >= 5*3*Cm*Cout) return;
  int o = e % Cout;
  int t = e / Cout;
  int m = t % Cm; t /= Cm;
  int k = t % 3; int g = t/3;
  twT[e] = tw[(size_t)g*Cout*Cm*3 + (o*Cm+m)*3 + k];
}

template<int Cm, int Cin, int Cout>
__global__ __launch_bounds__(256) void prep_gemm(
    const float* __restrict__ twT, const float* __restrict__ swe,
    const float* __restrict__ bg, float* __restrict__ WC){
  constexpr int CT = 256/Cout;
  __shared__ float sS[Cm*CT];
  int g = blockIdx.x, k = blockIdx.y, cz = blockIdx.z;
  int tid = threadIdx.x;
  for (int i=tid; i<Cm*CT; i+=256){
    int m = i/CT, cc = i%CT;
    sS[i] = swe[(size_t)g*Cm*Cin + m*Cin + cz*CT + cc];
  }
  __syncthreads();
  int o = tid % Cout, cc = tid / Cout;
  const float* tp = twT + ((size_t)(g*3+k)*Cm)*Cout + o;
  float acc = 0.f;
  #pragma unroll 4
  for (int m=0;m<Cm;m++) acc += tp[(size_t)m*Cout]*sS[m*CT+cc];
  int c = cz*CT + cc;
  WC[(size_t)g*3*Cin*Cout + ((size_t)k*Cin + c)*Cout + o] = bg[g*Cout+o]*BNS*acc;
}

__global__ __launch_bounds__(256) void prep_rw(
    const float* __restrict__ rw2, const float* __restrict__ rg2, const float* __restrict__ bg2,
    const float* __restrict__ rw3, const float* __restrict__ rg3, const float* __restrict__ bg3,
    float* __restrict__ RW2, float* __restrict__ RW3){
  int i = blockIdx.x*256 + threadIdx.x;
  if (i < 40960){ int g=i/8192, r=i%8192, c=r>>7, o=r&127;
    RW2[i] = bg2[g*128+o]*BNS*rg2[g*128+o]*BNS*rw2[(size_t)g*8192 + o*64 + c];
  } else if (i < 81920){ int j=i-40960; int g=j/8192, r=j%8192, c=r>>6, o=r&63;
    RW3[j] = bg3[g*64+o]*BNS*rg3[g*64+o]*BNS*rw3[(size_t)g*8192 + o*128 + c];
  }
}

__global__ __launch_bounds__(128) void prep_bias(
    const float* __restrict__ twT1, const float* __restrict__ twT2, const float* __restrict__ twT3,
    const float* __restrict__ sb1, const float* __restrict__ tb1, const float* __restrict__ bg1, const float* __restrict__ bb1,
    const float* __restrict__ sb2, const float* __restrict__ tb2, const float* __restrict__ bg2, const float* __restrict__ bb2,
    const float* __restrict__ rb2, const float* __restrict__ rg2, const float* __restrict__ rbb2,
    const float* __restrict__ sb3, const float* __restrict__ tb3, const float* __restrict__ bg3, const float* __restrict__ bb3,
    const float* __restrict__ rb3, const float* __restrict__ rg3, const float* __restrict__ rbb3,
    float* __restrict__ B1, float* __restrict__ RS1, float* __restrict__ B2, float* __restrict__ B3){
  __shared__ float sbe[128];
  int g = blockIdx.x, L = blockIdx.y, tid = threadIdx.x;
  if (L == 0){
    if (tid<64) sbe[tid] = sb1[g*192+tid] + sb1[g*192+64+tid] + sb1[g*192+128+tid];
    __syncthreads();
    if (tid<64){ int o=tid; float gsc = bg1[g*64+o]*BNS;
      for (int k=0;k<3;k++){ float s=0.f; const float* tp = twT1 + ((size_t)(g*3+k)*64)*64 + o;
        for (int m=0;m<64;m++) s += tp[m*64]*sbe[m];
        B1[g*256+(k+1)*64+o] = gsc*s; }
      B1[g*256+o] = gsc*tb1[g*64+o] + bb1[g*64+o];
      RS1[g*64+o] = gsc;
    }
  } else if (L == 1){
    sbe[tid] = sb2[g*384+tid] + sb2[g*384+128+tid] + sb2[g*384+256+tid];
    __syncthreads();
    { int o=tid; float gsc = bg2[g*128+o]*BNS; float rgs = rg2[g*128+o]*BNS;
      for (int k=0;k<3;k++){ float s=0.f; const float* tp = twT2 + ((size_t)(g*3+k)*128)*128 + o;
        for (int m=0;m<128;m++) s += tp[m*128]*sbe[m];
        B2[g*512+(k+1)*128+o] = gsc*s; }
      B2[g*512+o] = gsc*(tb2[g*128+o] + rgs*rb2[g*128+o] + rbb2[g*128+o]) + bb2[g*128+o];
    }
  } else {
    if (tid<64) sbe[tid] = sb3[g*192+tid] + sb3[g*192+64+tid] + sb3[g*192+128+tid];
    __syncthreads();
    if (tid<64){ int o=tid; float gsc = bg3[g*64+o]*BNS; float rgs = rg3[g*64+o]*BNS;
      for (int k=0;k<3;k++){ float s=0.f; const float* tp = twT3 + ((size_t)(g*3+k)*64)*64 + o;
        for (int m=0;m<64;m++) s += tp[m*64]*sbe[m];
        B3[g*256+(k+1)*64+o] = gsc*s; }
      B3[g*256+o] = gsc*(tb3[g*64+o] + rgs*rb3[g*64+o] + rbb3[g*64+o]) + bb3[g*64+o];
    }
  }
}

// ---------------- fused ST layer (R3 shape + bounded G-batched ds reads) -----
// MODE 1: embed fused from x, identity residual (scaled), write out
// MODE 2: residual matmul RW, write out (Cout split over blockIdx.z)
// MODE 3: residual matmul RW, fused (T,V)-sum -> atomicAdd into feat
// COS = full Cout stride of W/RW/BV/out; each block computes 64 outputs.
// Geometry: o = lane&31 (32 o-lanes, OP=2), sg in {0..7} -> broadcast ds reads
// (1-2 addresses per wave half: conflict-free). k loop unroll 1 + c4 unroll 2
// (R3-proven no-spill shape); G-batched xr reads amortize LDS latency.
// NEVER fully unroll k here: R4/R5/R6 all spilled (even at 256 VGPRs) when
// the scheduler hoisted read batches across the 24 unrolled (k,c4) iters.
template<int Cin, int COS, int NJ, int MODE>
__global__ __launch_bounds__(256) void st_layer(
    const float* __restrict__ in, float* __restrict__ out,
    const float* __restrict__ W, const float* __restrict__ RW,
    const float* __restrict__ BV, const float* __restrict__ RS,
    const float* __restrict__ adjg, const float* __restrict__ ew,
    const float* __restrict__ eb, int gstart)
{
  constexpr int TC = 16;
  constexpr int SE = (TC+2)*NJ;
  constexpr int SITES = TC*NJ;
  constexpr int SP = SITES/8;      // sites per thread (12/10/8)
  constexpr int OP = 2;            // 64 outputs per block / 32 o-lanes
  constexpr int NCH = Cin/32;
  constexpr int G = (SP%4==0) ? 4 : 5;   // ds-read batch (bounded live range)
  __shared__ float sIn[SE*32];
  __shared__ float sXg[SE*32];
  __shared__ float sAdj[NJ*NJ];
  __shared__ float sX3[MODE==1 ? SE*3 : 1];
  const int tid = threadIdx.x;
  const int b = blockIdx.y;
  const int t0 = blockIdx.x*TC;
  const int ooff = blockIdx.z*64;
  W += ooff; BV += ooff;
  if (MODE != 1) RW += ooff;
  if (MODE == 2) out += ooff;

  if (tid < NJ*NJ) sAdj[tid] = adjg[tid];
  if (MODE == 1){
    for (int e=tid; e<SE*3; e+=256){
      int se = e/3, j = e - se*3;
      int tl = se/NJ; int u = se - tl*NJ; int t = t0 + tl - 1;
      float v = 0.f;
      if (t>=0 && t<T_){ int joint = d_perm[gstart+u]; v = in[(((size_t)b*T_ + t)*25 + joint)*3 + j]; }
      sX3[e] = v;
    }
  }

  const int lane = tid & 63;
  const int o = lane & 31;
  const int sg = (tid>>6)*2 + (lane>>5);
  const int s0 = sg*SP;

  float acc[SP][OP];
  {
    float bno[OP], bk0[OP], bk1[OP], bk2[OP];
    #pragma unroll
    for (int j=0;j<OP;j++){ int oj = j*32 + o;
      bno[j]=BV[oj]; bk0[j]=BV[COS+oj]; bk1[j]=BV[2*COS+oj]; bk2[j]=BV[3*COS+oj]; }
    #pragma unroll
    for (int i=0;i<SP;i++){
      int s = s0 + i; int tg = t0 + s/NJ;
      #pragma unroll
      for (int j=0;j<OP;j++)
        acc[i][j] = bno[j] + bk1[j] + (tg>0 ? bk0[j] : 0.f) + (tg<T_-1 ? bk2[j] : 0.f);
    }
  }

  #pragma unroll 1
  for (int cz=0; cz<NCH; ++cz){
    __syncthreads();   // protects prior-chunk reads (and sAdj/sX3 on cz==0)
    // ---- stage input chunk [SE][32]
    if (MODE == 1){
      int cg = cz*32 + (tid & 31);
      float w0 = ew[cg*3], w1 = ew[cg*3+1], w2 = ew[cg*3+2], b0 = eb[cg];
      for (int e=tid; e<SE*32; e+=256){
        int se = e>>5; int t = t0 + se/NJ - 1;
        float v = 0.f;
        if (t>=0 && t<T_) v = b0 + sX3[se*3]*w0 + sX3[se*3+1]*w1 + sX3[se*3+2]*w2;
        sIn[e] = v;
      }
    } else {
      for (int e4=tid; e4<SE*8; e4+=256){
        int se = e4>>3; int cc = (e4&7)<<2;
        int tl = se/NJ; int u = se - tl*NJ; int t = t0 + tl - 1;
        float4 v = make_float4(0.f,0.f,0.f,0.f);
        if (t>=0 && t<T_) v = *(const float4*)&in[(((size_t)b*T_ + t)*NJ + u)*(size_t)Cin + cz*32 + cc];
        *(float4*)&sIn[se*32+cc] = v;
      }
    }
    __syncthreads();
    // ---- xg chunk = adj @ in
    for (int e=tid; e<SE*32; e+=256){
      int se = e>>5; int c = e&31; int u = se%NJ; int base = (se-u)*32 + c;
      float a = 0.f;
      #pragma unroll
      for (int v=0; v<NJ; v++) a += sAdj[u*NJ+v]*sIn[base + v*32];
      sXg[e] = a;
    }
    __syncthreads();
    // ---- partial conv over this chunk (k unroll 1, c4 unroll 2, G-batch)
    #pragma unroll 1
    for (int k=0;k<3;k++){
      const float* Wk = W + (size_t)(k*Cin + cz*32)*COS;
      #pragma unroll 2
      for (int c4=0;c4<32;c4+=4){
        float wv[4][OP];
        #pragma unroll
        for (int q=0;q<4;q++)
          #pragma unroll
          for (int j=0;j<OP;j++) wv[q][j] = Wk[(size_t)(c4+q)*COS + j*32 + o];
        #pragma unroll
        for (int i0=0;i0<SP;i0+=G){
          float4 xr[G];
          #pragma unroll
          for (int u=0;u<G;u++)
            xr[u] = *(const float4*)&sXg[(s0+i0+u+k*NJ)*32 + c4];
          #pragma unroll
          for (int u=0;u<G;u++)
            #pragma unroll
            for (int j=0;j<OP;j++)
              acc[i0+u][j] += xr[u].x*wv[0][j] + xr[u].y*wv[1][j] + xr[u].z*wv[2][j] + xr[u].w*wv[3][j];
        }
      }
    }
    // ---- partial residual over this chunk
    if (MODE == 1){
      // output channel cz*32+o lives in acc[.][cz]; static indices via branch.
      float rsv = RS[cz*32 + o];
      if (cz == 0){
        #pragma unroll
        for (int i0=0;i0<SP;i0+=G){
          float xr[G];
          #pragma unroll
          for (int u=0;u<G;u++) xr[u] = sIn[(s0+i0+u+NJ)*32 + o];
          #pragma unroll
          for (int u=0;u<G;u++) acc[i0+u][0] += xr[u]*rsv;
        }
      } else {
        #pragma unroll
        for (int i0=0;i0<SP;i0+=G){
          float xr[G];
          #pragma unroll
          for (int u=0;u<G;u++) xr[u] = sIn[(s0+i0+u+NJ)*32 + o];
          #pragma unroll
          for (int u=0;u<G;u++) acc[i0+u][1] += xr[u]*rsv;
        }
      }
    } else {
      #pragma unroll 2
      for (int c4=0;c4<32;c4+=4){
        float rv[4][OP];
        #pragma unroll
        for (int q=0;q<4;q++)
          #pragma unroll
          for (int j=0;j<OP;j++) rv[q][j] = RW[(size_t)(cz*32+c4+q)*COS + j*32 + o];
        #pragma unroll
        for (int i0=0;i0<SP;i0+=G){
          float4 xr[G];
          #pragma unroll
          for (int u=0;u<G;u++)
            xr[u] = *(const float4*)&sIn[(s0+i0+u+NJ)*32 + c4];
          #pragma unroll
          for (int u=0;u<G;u++)
            #pragma unroll
            for (int j=0;j<OP;j++)
              acc[i0+u][j] += xr[u].x*rv[0][j] + xr[u].y*rv[1][j] + xr[u].z*rv[2][j] + xr[u].w*rv[3][j];
        }
      }
    }
  }
  // ---- epilogue
  if (MODE == 3){
    #pragma unroll
    for (int j=0;j<OP;j++){
      float sum = 0.f;
      #pragma unroll
      for (int i=0;i<SP;i++) sum += fmaxf(acc[i][j], 0.f);
      atomicAdd(&out[(size_t)b*64 + j*32 + o], sum);
    }
  } else {
    size_t obase = ((size_t)b*T_ + t0)*NJ*COS;
    #pragma unroll
    for (int i=0;i<SP;i++)
      #pragma unroll
      for (int j=0;j<OP;j++)
        out[obase + (size_t)(s0+i)*COS + j*32 + o] = fmaxf(acc[i][j], 0.f);
  }
}

// ---------------- VQ ---------------------------------------------------------
__global__ __launch_bounds__(128) void vq_kernel(const float* __restrict__ feat,
    const float* __restrict__ cb, float* __restrict__ dout){
  int b = blockIdx.x, g = blockIdx.y, tid = threadIdx.x;
  __shared__ float sF[64];
  __shared__ float sD[128]; __shared__ int sI[128];
  __shared__ float sL[64];
  float inv = 1.0f/(256.0f*(float)d_gn[g]);
  if (tid < 64) sF[tid] = feat[((size_t)g*64 + b)*64 + tid]*inv;
  __syncthreads();
  const float* cbg = cb + (size_t)g*128*64;
  {
    const float* c = cbg + (size_t)tid*64;
    float d = 0.f;
    for (int i=0;i<64;i++){ float df = c[i]-sF[i]; d += df*df; }
    sD[tid] = d; sI[tid] = tid;
  }
  __syncthreads();
  for (int s=64; s>0; s>>=1){
    if (tid < s){
      float d2 = sD[tid+s]; int i2 = sI[tid+s];
      if (d2 < sD[tid] || (d2 == sD[tid] && i2 < sI[tid])){ sD[tid]=d2; sI[tid]=i2; }
    }
    __syncthreads();
  }
  int idx = sI[0];
  if (tid < 64){
    float q = cbg[(size_t)idx*64 + tid];
    dout[((size_t)g*64 + b)*64 + tid] = q;
    float df = q - sF[tid];
    sL[tid] = df*df;
  }
  __syncthreads();
  if (tid == 0){
    float s = 0.f;
    for (int i=0;i<64;i++) s += sL[i];
    atomicAdd(dout + 20480, 1.25f*s/4096.0f);
    dout[20481 + g*64 + b] = (float)idx;
  }
}

// ---------------- dispatch helpers ------------------------------------------
static void launch_st1(int nj, hipStream_t s, const float* x, float* A1,
    const float* WC, const float* BV, const float* RS, const float* adj,
    const float* ew, const float* eb, int gstart){
  dim3 grid(T_/16, B_, 1);
  switch(nj){
    case 4: st_layer<64,64,4,1><<<grid,256,0,s>>>(x,A1,WC,nullptr,BV,RS,adj,ew,eb,gstart); break;
    case 5: st_layer<64,64,5,1><<<grid,256,0,s>>>(x,A1,WC,nullptr,BV,RS,adj,ew,eb,gstart); break;
    case 6: st_layer<64,64,6,1><<<grid,256,0,s>>>(x,A1,WC,nullptr,BV,RS,adj,ew,eb,gstart); break;
  }
}
static void launch_st2(int nj, hipStream_t s, const float* A1, float* A2,
    const float* WC, const float* RW, const float* BV, const float* adj){
  dim3 grid(T_/16, B_, 2);
  switch(nj){
    case 4: st_layer<64,128,4,2><<<grid,256,0,s>>>(A1,A2,WC,RW,BV,nullptr,adj,nullptr,nullptr,0); break;
    case 5: st_layer<64,128,5,2><<<grid,256,0,s>>>(A1,A2,WC,RW,BV,nullptr,adj,nullptr,nullptr,0); break;
    case 6: st_layer<64,128,6,2><<<grid,256,0,s>>>(A1,A2,WC,RW,BV,nullptr,adj,nullptr,nullptr,0); break;
  }
}
static void launch_st3(int nj, hipStream_t s, const float* A2, float* featg,
    const float* WC, const float* RW, const float* BV, const float* adj){
  dim3 grid(T_/16, B_, 1);
  switch(nj){
    case 4: st_layer<128,64,4,3><<<grid,256,0,s>>>(A2,featg,WC,RW,BV,nullptr,adj,nullptr,nullptr,0); break;
    case 5: st_layer<128,64,5,3><<<grid,256,0,s>>>(A2,featg,WC,RW,BV,nullptr,adj,nullptr,nullptr,0); break;
    case 6: st_layer<128,64,6,3><<<grid,256,0,s>>>(A2,featg,WC,RW,BV,nullptr,adj,nullptr,nullptr,0); break;
  }
}

extern "C" void kernel_launch(void* const* d_in, const int* in_sizes, int n_in,
                              void* d_out, int out_size, void* d_ws, size_t ws_size,
                              hipStream_t stream) {
  const float* x    = (const float*)d_in[0];
  const float* ew   = (const float*)d_in[1];
  const float* eb   = (const float*)d_in[2];
  const float* sw1  = (const float*)d_in[3];
  const float* sb1  = (const float*)d_in[4];
  const float* tw1  = (const float*)d_in[5];
  const float* tb1  = (const float*)d_in[6];
  const float* bg1  = (const float*)d_in[7];
  const float* bb1  = (const float*)d_in[8];
  const float* rw2  = (const float*)d_in[9];
  const float* rb2  = (const float*)d_in[10];
  const float* rg2  = (const float*)d_in[11];
  const float* rbb2 = (const float*)d_in[12];
  const float* sw2  = (const float*)d_in[13];
  const float* sb2  = (const float*)d_in[14];
  const float* tw2  = (const float*)d_in[15];
  const float* tb2  = (const float*)d_in[16];
  const float* bg2  = (const float*)d_in[17];
  const float* bb2  = (const float*)d_in[18];
  const float* rw3  = (const float*)d_in[19];
  const float* rb3  = (const float*)d_in[20];
  const float* rg3  = (const float*)d_in[21];
  const float* rbb3 = (const float*)d_in[22];
  const float* sw3  = (const float*)d_in[23];
  const float* sb3  = (const float*)d_in[24];
  const float* tw3  = (const float*)d_in[25];
  const float* tb3  = (const float*)d_in[26];
  const float* bg3  = (const float*)d_in[27];
  const float* bb3  = (const float*)d_in[28];
  const float* cbs  = (const float*)d_in[29];
  float* dout = (float*)d_out;
  float* ws = (float*)d_ws;

  const size_t OFF_ADJ = 0;
  const size_t OFF_WC1 = 256;
  const size_t OFF_B1  = 61696;
  const size_t OFF_RS1 = 62976;
  const size_t OFF_WC2 = 63296;
  const size_t OFF_RW2 = 186176;
  const size_t OFF_B2  = 227136;
  const size_t OFF_WC3 = 229696;
  const size_t OFF_RW3 = 352576;
  const size_t OFF_B3  = 393536;
  const size_t OFF_FEAT= 394816;
  const size_t OFF_A1  = 415296;
  const size_t OFF_A2  = 6706752;
  const size_t WS_FLOATS = 19289664;
  if (ws_size < WS_FLOATS*sizeof(float)) return; // insufficient workspace -> fail loudly at validation

  float* adj5 = ws + OFF_ADJ;
  float* WC1  = ws + OFF_WC1;  float* B1 = ws + OFF_B1;  float* RS1 = ws + OFF_RS1;
  float* WC2  = ws + OFF_WC2;  float* RW2 = ws + OFF_RW2; float* B2 = ws + OFF_B2;
  float* WC3  = ws + OFF_WC3;  float* RW3 = ws + OFF_RW3; float* B3 = ws + OFF_B3;
  float* feat = ws + OFF_FEAT;
  float* A1   = ws + OFF_A1;
  float* A2   = ws + OFF_A2;

  // prep-phase scratch aliased into the A2 region (dead until st2 writes it)
  float* twT1 = A2;            // 61440
  float* twT2 = A2 + 61440;    // 245760
  float* twT3 = A2 + 307200;   // 61440
  float* swe1 = A2 + 368640;   // 20480
  float* swe2 = A2 + 389120;   // 40960
  float* swe3 = A2 + 430080;   // 40960

  zero_kernel<<<80, 256, 0, stream>>>(feat, dout + 20480);
  adj_kernel<<<1, 64, 0, stream>>>(adj5);
  fold_swe<<<400, 256, 0, stream>>>(sw1, sw2, sw3, swe1, swe2, swe3);
  transpose_tw<64,64>  <<<240, 256, 0, stream>>>(tw1, twT1);
  transpose_tw<128,128><<<960, 256, 0, stream>>>(tw2, twT2);
  transpose_tw<64,64>  <<<240, 256, 0, stream>>>(tw3, twT3);
  prep_gemm<64,64,64>  <<<dim3(5,3,16), 256, 0, stream>>>(twT1, swe1, bg1, WC1);
  prep_gemm<128,64,128><<<dim3(5,3,32), 256, 0, stream>>>(twT2, swe2, bg2, WC2);
  prep_gemm<64,128,64> <<<dim3(5,3,32), 256, 0, stream>>>(twT3, swe3, bg3, WC3);
  prep_rw<<<320, 256, 0, stream>>>(rw2, rg2, bg2, rw3, rg3, bg3, RW2, RW3);
  prep_bias<<<dim3(5,3), 128, 0, stream>>>(twT1, twT2, twT3,
      sb1, tb1, bg1, bb1,
      sb2, tb2, bg2, bb2, rb2, rg2, rbb2,
      sb3, tb3, bg3, bb3, rb3, rg3, rbb3,
      B1, RS1, B2, B3);

  const int h_gn[5] = {5,6,6,4,4};
  const int h_gstart[5] = {0,5,11,17,21};
  for (int g=0; g<5; g++){
    int nj = h_gn[g];
    launch_st1(nj, stream, x, A1, WC1 + (size_t)g*12288, B1 + g*256, RS1 + g*64,
               adj5 + g*36, ew, eb, h_gstart[g]);
    launch_st2(nj, stream, A1, A2, WC2 + (size_t)g*24576, RW2 + (size_t)g*8192,
               B2 + g*512, adj5 + g*36);
    launch_st3(nj, stream, A2, feat + (size_t)g*4096, WC3 + (size_t)g*24576,
               RW3 + (size_t)g*8192, B3 + g*256, adj5 + g*36);
  }
  vq_kernel<<<dim3(B_,5), 128, 0, stream>>>(feat, cbs, dout);
}

// Round 11
// 1534.782 us; speedup vs baseline: 9.3432x; 1.0467x over previous
//
#include <hip/hip_runtime.h>

#define T_ 256
#define B_ 64
static constexpr float BNS = 0.9999950000374997f; // 1/sqrt(1+1e-5)

__device__ __constant__ int d_perm[25] = {0,1,2,3,20, 4,5,6,7,21,22, 8,9,10,11,23,24, 12,13,14,15, 16,17,18,19};
__device__ __constant__ int d_gstart[5] = {0,5,11,17,21};
__device__ __constant__ int d_gn[5] = {5,6,6,4,4};
// 0-indexed valid skeleton edges (entries (1,0),(0,12),(0,16) of the 1-indexed
// list go out of bounds after -1 and are skipped by the reference)
__device__ __constant__ int d_edges[21][2] = {
  {2,1},{1,19},{19,0},{19,3},{3,4},{4,5},{5,21},{5,6},{6,20},{19,7},
  {7,8},{8,9},{9,23},{9,10},{10,22},{11,12},{12,13},{13,14},{15,16},{16,17},{17,18}};

// ---------------- adjacency (fp64, exact reproduction of _sub_adj) -----------
__global__ void adj_kernel(float* __restrict__ adjout){ // [5][36], row stride = n (compact), zero padded
  if (threadIdx.x != 0 || blockIdx.x != 0) return;
  double fa[25][25];
  for (int i=0;i<25;i++) for (int j=0;j<25;j++) fa[i][j]=0.0;
  for (int e=0;e<21;e++){ int i=d_edges[e][0], j=d_edges[e][1]; fa[i][j]=1.0; fa[j][i]=1.0; }
  for (int i=0;i<25;i++) fa[i][i] += 1.0;
  for (int i=0;i<25;i++){
    double dg=0; for (int j=0;j<25;j++) dg += fa[i][j];
    if (dg==0.0) dg=1.0;
    for (int j=0;j<25;j++) fa[i][j] /= dg;
  }
  for (int g=0; g<5; g++){
    int n = d_gn[g]; int gs = d_gstart[g];
    for (int q=0;q<36;q++) adjout[g*36+q] = 0.f;
    double sa[6][6];
    for (int a=0;a<n;a++) for (int b=0;b<n;b++) sa[a][b] = fa[d_perm[gs+a]][d_perm[gs+b]];
    for (int a=0;a<n;a++) sa[a][a] += 1.0;            // n>1 for all groups
    double deg[6];
    for (int a=0;a<n;a++){ double s=0; for (int b=0;b<n;b++) s += sa[a][b]; deg[a]=s; }
    for (int a=1;a<n;a++) if (deg[a]==1.0){ sa[0][a]=1.0; sa[a][0]=1.0; }
    for (int a=0;a<n;a++){
      double s=0; for (int b=0;b<n;b++) s += sa[a][b];
      if (s==0.0) s=1.0;
      for (int b=0;b<n;b++) adjout[g*36 + a*n + b] = (float)(sa[a][b]/s);
    }
  }
}

__global__ void zero_kernel(float* __restrict__ feat, float* __restrict__ loss){
  int i = blockIdx.x*256 + threadIdx.x;
  if (i < 5*64*64) feat[i] = 0.f;
  if (i == 0) loss[0] = 0.f;
}

// ---------------- parallel weight prep --------------------------------------
__global__ __launch_bounds__(256) void fold_swe(
    const float* __restrict__ sw1, const float* __restrict__ sw2, const float* __restrict__ sw3,
    float* __restrict__ swe1, float* __restrict__ swe2, float* __restrict__ swe3){
  int i = blockIdx.x*256 + threadIdx.x;
  if (i < 20480){ int g=i/4096, r=i%4096;
    swe1[i] = sw1[g*12288 + r] + sw1[g*12288 + 4096 + r] + sw1[g*12288 + 8192 + r];
  } else if (i < 61440){ int j=i-20480; int g=j/8192, r=j%8192;
    swe2[j] = sw2[g*24576 + r] + sw2[g*24576 + 8192 + r] + sw2[g*24576 + 16384 + r];
  } else if (i < 102400){ int j=i-61440; int g=j/8192, r=j%8192;
    swe3[j] = sw3[g*24576 + r] + sw3[g*24576 + 8192 + r] + sw3[g*24576 + 16384 + r];
  }
}

template<int Cm, int Cout>
__global__ __launch_bounds__(256) void transpose_tw(const float* __restrict__ tw, float* __restrict__ twT){
  int e = blockIdx.x*256 + threadIdx.x;
  if (e >= 5*3*Cm*Cout) return;
  int o = e % Cout;
  int t = e / Cout;
  int m = t % Cm; t /= Cm;
  int k = t % 3; int g = t/3;
  twT[e] = tw[(size_t)g*Cout*Cm*3 + (o*Cm+m)*3 + k];
}

template<int Cm, int Cin, int Cout>
__global__ __launch_bounds__(256) void prep_gemm(
    const float* __restrict__ twT, const float* __restrict__ swe,
    const float* __restrict__ bg, float* __restrict__ WC){
  constexpr int CT = 256/Cout;
  __shared__ float sS[Cm*CT];
  int g = blockIdx.x, k = blockIdx.y, cz = blockIdx.z;
  int tid = threadIdx.x;
  for (int i=tid; i<Cm*CT; i+=256){
    int m = i/CT, cc = i%CT;
    sS[i] = swe[(size_t)g*Cm*Cin + m*Cin + cz*CT + cc];
  }
  __syncthreads();
  int o = tid % Cout, cc = tid / Cout;
  const float* tp = twT + ((size_t)(g*3+k)*Cm)*Cout + o;
  float acc = 0.f;
  #pragma unroll 4
  for (int m=0;m<Cm;m++) acc += tp[(size_t)m*Cout]*sS[m*CT+cc];
  int c = cz*CT + cc;
  WC[(size_t)g*3*Cin*Cout + ((size_t)k*Cin + c)*Cout + o] = bg[g*Cout+o]*BNS*acc;
}

__global__ __launch_bounds__(256) void prep_rw(
    const float* __restrict__ rw2, const float* __restrict__ rg2, const float* __restrict__ bg2,
    const float* __restrict__ rw3, const float* __restrict__ rg3, const float* __restrict__ bg3,
    float* __restrict__ RW2, float* __restrict__ RW3){
  int i = blockIdx.x*256 + threadIdx.x;
  if (i < 40960){ int g=i/8192, r=i%8192, c=r>>7, o=r&127;
    RW2[i] = bg2[g*128+o]*BNS*rg2[g*128+o]*BNS*rw2[(size_t)g*8192 + o*64 + c];
  } else if (i < 81920){ int j=i-40960; int g=j/8192, r=j%8192, c=r>>6, o=r&63;
    RW3[j] = bg3[g*64+o]*BNS*rg3[g*64+o]*BNS*rw3[(size_t)g*8192 + o*128 + c];
  }
}

__global__ __launch_bounds__(128) void prep_bias(
    const float* __restrict__ twT1, const float* __restrict__ twT2, const float* __restrict__ twT3,
    const float* __restrict__ sb1, const float* __restrict__ tb1, const float* __restrict__ bg1, const float* __restrict__ bb1,
    const float* __restrict__ sb2, const float* __restrict__ tb2, const float* __restrict__ bg2, const float* __restrict__ bb2,
    const float* __restrict__ rb2, const float* __restrict__ rg2, const float* __restrict__ rbb2,
    const float* __restrict__ sb3, const float* __restrict__ tb3, const float* __restrict__ bg3, const float* __restrict__ bb3,
    const float* __restrict__ rb3, const float* __restrict__ rg3, const float* __restrict__ rbb3,
    float* __restrict__ B1, float* __restrict__ RS1, float* __restrict__ B2, float* __restrict__ B3){
  __shared__ float sbe[128];
  int g = blockIdx.x, L = blockIdx.y, tid = threadIdx.x;
  if (L == 0){
    if (tid<64) sbe[tid] = sb1[g*192+tid] + sb1[g*192+64+tid] + sb1[g*192+128+tid];
    __syncthreads();
    if (tid<64){ int o=tid; float gsc = bg1[g*64+o]*BNS;
      for (int k=0;k<3;k++){ float s=0.f; const float* tp = twT1 + ((size_t)(g*3+k)*64)*64 + o;
        for (int m=0;m<64;m++) s += tp[m*64]*sbe[m];
        B1[g*256+(k+1)*64+o] = gsc*s; }
      B1[g*256+o] = gsc*tb1[g*64+o] + bb1[g*64+o];
      RS1[g*64+o] = gsc;
    }
  } else if (L == 1){
    sbe[tid] = sb2[g*384+tid] + sb2[g*384+128+tid] + sb2[g*384+256+tid];
    __syncthreads();
    { int o=tid; float gsc = bg2[g*128+o]*BNS; float rgs = rg2[g*128+o]*BNS;
      for (int k=0;k<3;k++){ float s=0.f; const float* tp = twT2 + ((size_t)(g*3+k)*128)*128 + o;
        for (int m=0;m<128;m++) s += tp[m*128]*sbe[m];
        B2[g*512+(k+1)*128+o] = gsc*s; }
      B2[g*512+o] = gsc*(tb2[g*128+o] + rgs*rb2[g*128+o] + rbb2[g*128+o]) + bb2[g*128+o];
    }
  } else {
    if (tid<64) sbe[tid] = sb3[g*192+tid] + sb3[g*192+64+tid] + sb3[g*192+128+tid];
    __syncthreads();
    if (tid<64){ int o=tid; float gsc = bg3[g*64+o]*BNS; float rgs = rg3[g*64+o]*BNS;
      for (int k=0;k<3;k++){ float s=0.f; const float* tp = twT3 + ((size_t)(g*3+k)*64)*64 + o;
        for (int m=0;m<64;m++) s += tp[m*64]*sbe[m];
        B3[g*256+(k+1)*64+o] = gsc*s; }
      B3[g*256+o] = gsc*(tb3[g*64+o] + rgs*rb3[g*64+o] + rbb3[g*64+o]) + bb3[g*64+o];
    }
  }
}

// ---------------- fused ST layer (tap-merged conv: each xg row read once) ----
// MODE 1: embed fused from x, identity residual (scaled), write out
// MODE 2: residual matmul RW, write out (Cout split over blockIdx.z)
// MODE 3: residual matmul RW, fused (T,V)-sum -> atomicAdd into feat
// COS = full Cout stride of W/RW/BV/out; each block computes 64 outputs.
// Geometry: o = lane&31 (OP=2), sg in {0..7}, SP = 2*NJ (TC=16).
// Conv rows r in [0,4NJ): row r feeds acc[r-k*NJ] with tap k when valid.
// 4 static ranges of NJ rows each -> every xg row ds_read ONCE (24 reads vs
// 36 in the k-loop form), all 24 tap-weights loaded once per c4 (one vmcnt
// wait per 288 FMAs). Summation order per acc: c4-outer, k-ascending-inner —
// reassociated vs reference, safe: quants/idx outputs are discrete (codebook
// copies / argmin), loss tolerance >> 1e-6.
// c4 loop stays `#pragma unroll 1`: R4-R6 showed unrolling the outer loop
// around read batches makes the scheduler hoist whole batches -> 4GB spills.
template<int Cin, int COS, int NJ, int MODE>
__global__ __launch_bounds__(256) void st_layer(
    const float* __restrict__ in, float* __restrict__ out,
    const float* __restrict__ W, const float* __restrict__ RW,
    const float* __restrict__ BV, const float* __restrict__ RS,
    const float* __restrict__ adjg, const float* __restrict__ ew,
    const float* __restrict__ eb, int gstart)
{
  constexpr int TC = 16;
  constexpr int SE = (TC+2)*NJ;
  constexpr int SITES = TC*NJ;
  constexpr int SP = SITES/8;      // sites per thread (12/10/8)
  static_assert(SP == 2*NJ, "tap-merge ranges assume SP == 2*NJ (TC=16)");
  constexpr int OP = 2;            // 64 outputs per block / 32 o-lanes
  constexpr int NCH = Cin/32;
  constexpr int G = (SP%4==0) ? 4 : 5;   // residual ds-read batch
  __shared__ float sIn[SE*32];
  __shared__ float sXg[SE*32];
  __shared__ float sAdj[NJ*NJ];
  __shared__ float sX3[MODE==1 ? SE*3 : 1];
  const int tid = threadIdx.x;
  const int b = blockIdx.y;
  const int t0 = blockIdx.x*TC;
  const int ooff = blockIdx.z*64;
  W += ooff; BV += ooff;
  if (MODE != 1) RW += ooff;
  if (MODE == 2) out += ooff;

  if (tid < NJ*NJ) sAdj[tid] = adjg[tid];
  if (MODE == 1){
    for (int e=tid; e<SE*3; e+=256){
      int se = e/3, j = e - se*3;
      int tl = se/NJ; int u = se - tl*NJ; int t = t0 + tl - 1;
      float v = 0.f;
      if (t>=0 && t<T_){ int joint = d_perm[gstart+u]; v = in[(((size_t)b*T_ + t)*25 + joint)*3 + j]; }
      sX3[e] = v;
    }
  }

  const int lane = tid & 63;
  const int o = lane & 31;
  const int sg = (tid>>6)*2 + (lane>>5);
  const int s0 = sg*SP;

  float acc[SP][OP];
  {
    float bno[OP], bk0[OP], bk1[OP], bk2[OP];
    #pragma unroll
    for (int j=0;j<OP;j++){ int oj = j*32 + o;
      bno[j]=BV[oj]; bk0[j]=BV[COS+oj]; bk1[j]=BV[2*COS+oj]; bk2[j]=BV[3*COS+oj]; }
    #pragma unroll
    for (int i=0;i<SP;i++){
      int s = s0 + i; int tg = t0 + s/NJ;
      #pragma unroll
      for (int j=0;j<OP;j++)
        acc[i][j] = bno[j] + bk1[j] + (tg>0 ? bk0[j] : 0.f) + (tg<T_-1 ? bk2[j] : 0.f);
    }
  }

  #pragma unroll 1
  for (int cz=0; cz<NCH; ++cz){
    __syncthreads();   // protects prior-chunk reads (and sAdj/sX3 on cz==0)
    // ---- stage input chunk [SE][32]
    if (MODE == 1){
      int cg = cz*32 + (tid & 31);
      float w0 = ew[cg*3], w1 = ew[cg*3+1], w2 = ew[cg*3+2], b0 = eb[cg];
      for (int e=tid; e<SE*32; e+=256){
        int se = e>>5; int t = t0 + se/NJ - 1;
        float v = 0.f;
        if (t>=0 && t<T_) v = b0 + sX3[se*3]*w0 + sX3[se*3+1]*w1 + sX3[se*3+2]*w2;
        sIn[e] = v;
      }
    } else {
      for (int e4=tid; e4<SE*8; e4+=256){
        int se = e4>>3; int cc = (e4&7)<<2;
        int tl = se/NJ; int u = se - tl*NJ; int t = t0 + tl - 1;
        float4 v = make_float4(0.f,0.f,0.f,0.f);
        if (t>=0 && t<T_) v = *(const float4*)&in[(((size_t)b*T_ + t)*NJ + u)*(size_t)Cin + cz*32 + cc];
        *(float4*)&sIn[se*32+cc] = v;
      }
    }
    __syncthreads();
    // ---- xg chunk = adj @ in
    for (int e=tid; e<SE*32; e+=256){
      int se = e>>5; int c = e&31; int u = se%NJ; int base = (se-u)*32 + c;
      float a = 0.f;
      #pragma unroll
      for (int v=0; v<NJ; v++) a += sAdj[u*NJ+v]*sIn[base + v*32];
      sXg[e] = a;
    }
    __syncthreads();
    // ---- partial conv: tap-merged rows, c4 unroll 1
    #pragma unroll 1
    for (int c4=0;c4<32;c4+=4){
      const float* Wc = W + (size_t)(cz*32 + c4)*COS;
      float wv[3][4][OP];
      #pragma unroll
      for (int k=0;k<3;k++)
        #pragma unroll
        for (int q=0;q<4;q++)
          #pragma unroll
          for (int j=0;j<OP;j++)
            wv[k][q][j] = Wc[((size_t)k*Cin + q)*COS + j*32 + o];
      // range A: rows [0,NJ) -> tap0 into acc[r]
      {
        float4 xr[NJ];
        #pragma unroll
        for (int r=0;r<NJ;r++) xr[r] = *(const float4*)&sXg[(s0+r)*32 + c4];
        #pragma unroll
        for (int r=0;r<NJ;r++)
          #pragma unroll
          for (int j=0;j<OP;j++)
            acc[r][j] += xr[r].x*wv[0][0][j] + xr[r].y*wv[0][1][j] + xr[r].z*wv[0][2][j] + xr[r].w*wv[0][3][j];
      }
      // range B: rows [NJ,2NJ) -> tap0 into acc[NJ+r], tap1 into acc[r]
      {
        float4 xr[NJ];
        #pragma unroll
        for (int r=0;r<NJ;r++) xr[r] = *(const float4*)&sXg[(s0+NJ+r)*32 + c4];
        #pragma unroll
        for (int r=0;r<NJ;r++){
          #pragma unroll
          for (int j=0;j<OP;j++)
            acc[NJ+r][j] += xr[r].x*wv[0][0][j] + xr[r].y*wv[0][1][j] + xr[r].z*wv[0][2][j] + xr[r].w*wv[0][3][j];
          #pragma unroll
          for (int j=0;j<OP;j++)
            acc[r][j] += xr[r].x*wv[1][0][j] + xr[r].y*wv[1][1][j] + xr[r].z*wv[1][2][j] + xr[r].w*wv[1][3][j];
        }
      }
      // range C: rows [2NJ,3NJ) -> tap1 into acc[NJ+r], tap2 into acc[r]
      {
        float4 xr[NJ];
        #pragma unroll
        for (int r=0;r<NJ;r++) xr[r] = *(const float4*)&sXg[(s0+2*NJ+r)*32 + c4];
        #pragma unroll
        for (int r=0;r<NJ;r++){
          #pragma unroll
          for (int j=0;j<OP;j++)
            acc[NJ+r][j] += xr[r].x*wv[1][0][j] + xr[r].y*wv[1][1][j] + xr[r].z*wv[1][2][j] + xr[r].w*wv[1][3][j];
          #pragma unroll
          for (int j=0;j<OP;j++)
            acc[r][j] += xr[r].x*wv[2][0][j] + xr[r].y*wv[2][1][j] + xr[r].z*wv[2][2][j] + xr[r].w*wv[2][3][j];
        }
      }
      // range D: rows [3NJ,4NJ) -> tap2 into acc[NJ+r]
      {
        float4 xr[NJ];
        #pragma unroll
        for (int r=0;r<NJ;r++) xr[r] = *(const float4*)&sXg[(s0+3*NJ+r)*32 + c4];
        #pragma unroll
        for (int r=0;r<NJ;r++)
          #pragma unroll
          for (int j=0;j<OP;j++)
            acc[NJ+r][j] += xr[r].x*wv[2][0][j] + xr[r].y*wv[2][1][j] + xr[r].z*wv[2][2][j] + xr[r].w*wv[2][3][j];
      }
    }
    // ---- partial residual over this chunk
    if (MODE == 1){
      // output channel cz*32+o lives in acc[.][cz]; static indices via branch.
      float rsv = RS[cz*32 + o];
      if (cz == 0){
        #pragma unroll
        for (int i0=0;i0<SP;i0+=G){
          float xr[G];
          #pragma unroll
          for (int u=0;u<G;u++) xr[u] = sIn[(s0+i0+u+NJ)*32 + o];
          #pragma unroll
          for (int u=0;u<G;u++) acc[i0+u][0] += xr[u]*rsv;
        }
      } else {
        #pragma unroll
        for (int i0=0;i0<SP;i0+=G){
          float xr[G];
          #pragma unroll
          for (int u=0;u<G;u++) xr[u] = sIn[(s0+i0+u+NJ)*32 + o];
          #pragma unroll
          for (int u=0;u<G;u++) acc[i0+u][1] += xr[u]*rsv;
        }
      }
    } else {
      #pragma unroll 1
      for (int c4=0;c4<32;c4+=4){
        float rv[4][OP];
        #pragma unroll
        for (int q=0;q<4;q++)
          #pragma unroll
          for (int j=0;j<OP;j++) rv[q][j] = RW[(size_t)(cz*32+c4+q)*COS + j*32 + o];
        #pragma unroll
        for (int i0=0;i0<SP;i0+=G){
          float4 xr[G];
          #pragma unroll
          for (int u=0;u<G;u++)
            xr[u] = *(const float4*)&sIn[(s0+i0+u+NJ)*32 + c4];
          #pragma unroll
          for (int u=0;u<G;u++)
            #pragma unroll
            for (int j=0;j<OP;j++)
              acc[i0+u][j] += xr[u].x*rv[0][j] + xr[u].y*rv[1][j] + xr[u].z*rv[2][j] + xr[u].w*rv[3][j];
        }
      }
    }
  }
  // ---- epilogue
  if (MODE == 3){
    #pragma unroll
    for (int j=0;j<OP;j++){
      float sum = 0.f;
      #pragma unroll
      for (int i=0;i<SP;i++) sum += fmaxf(acc[i][j], 0.f);
      atomicAdd(&out[(size_t)b*64 + j*32 + o], sum);
    }
  } else {
    size_t obase = ((size_t)b*T_ + t0)*NJ*COS;
    #pragma unroll
    for (int i=0;i<SP;i++)
      #pragma unroll
      for (int j=0;j<OP;j++)
        out[obase + (size_t)(s0+i)*COS + j*32 + o] = fmaxf(acc[i][j], 0.f);
  }
}

// ---------------- VQ ---------------------------------------------------------
__global__ __launch_bounds__(128) void vq_kernel(const float* __restrict__ feat,
    const float* __restrict__ cb, float* __restrict__ dout){
  int b = blockIdx.x, g = blockIdx.y, tid = threadIdx.x;
  __shared__ float sF[64];
  __shared__ float sD[128]; __shared__ int sI[128];
  __shared__ float sL[64];
  float inv = 1.0f/(256.0f*(float)d_gn[g]);
  if (tid < 64) sF[tid] = feat[((size_t)g*64 + b)*64 + tid]*inv;
  __syncthreads();
  const float* cbg = cb + (size_t)g*128*64;
  {
    const float* c = cbg + (size_t)tid*64;
    float d = 0.f;
    for (int i=0;i<64;i++){ float df = c[i]-sF[i]; d += df*df; }
    sD[tid] = d; sI[tid] = tid;
  }
  __syncthreads();
  for (int s=64; s>0; s>>=1){
    if (tid < s){
      float d2 = sD[tid+s]; int i2 = sI[tid+s];
      if (d2 < sD[tid] || (d2 == sD[tid] && i2 < sI[tid])){ sD[tid]=d2; sI[tid]=i2; }
    }
    __syncthreads();
  }
  int idx = sI[0];
  if (tid < 64){
    float q = cbg[(size_t)idx*64 + tid];
    dout[((size_t)g*64 + b)*64 + tid] = q;
    float df = q - sF[tid];
    sL[tid] = df*df;
  }
  __syncthreads();
  if (tid == 0){
    float s = 0.f;
    for (int i=0;i<64;i++) s += sL[i];
    atomicAdd(dout + 20480, 1.25f*s/4096.0f);
    dout[20481 + g*64 + b] = (float)idx;
  }
}

// ---------------- dispatch helpers ------------------------------------------
static void launch_st1(int nj, hipStream_t s, const float* x, float* A1,
    const float* WC, const float* BV, const float* RS, const float* adj,
    const float* ew, const float* eb, int gstart){
  dim3 grid(T_/16, B_, 1);
  switch(nj){
    case 4: st_layer<64,64,4,1><<<grid,256,0,s>>>(x,A1,WC,nullptr,BV,RS,adj,ew,eb,gstart); break;
    case 5: st_layer<64,64,5,1><<<grid,256,0,s>>>(x,A1,WC,nullptr,BV,RS,adj,ew,eb,gstart); break;
    case 6: st_layer<64,64,6,1><<<grid,256,0,s>>>(x,A1,WC,nullptr,BV,RS,adj,ew,eb,gstart); break;
  }
}
static void launch_st2(int nj, hipStream_t s, const float* A1, float* A2,
    const float* WC, const float* RW, const float* BV, const float* adj){
  dim3 grid(T_/16, B_, 2);
  switch(nj){
    case 4: st_layer<64,128,4,2><<<grid,256,0,s>>>(A1,A2,WC,RW,BV,nullptr,adj,nullptr,nullptr,0); break;
    case 5: st_layer<64,128,5,2><<<grid,256,0,s>>>(A1,A2,WC,RW,BV,nullptr,adj,nullptr,nullptr,0); break;
    case 6: st_layer<64,128,6,2><<<grid,256,0,s>>>(A1,A2,WC,RW,BV,nullptr,adj,nullptr,nullptr,0); break;
  }
}
static void launch_st3(int nj, hipStream_t s, const float* A2, float* featg,
    const float* WC, const float* RW, const float* BV, const float* adj){
  dim3 grid(T_/16, B_, 1);
  switch(nj){
    case 4: st_layer<128,64,4,3><<<grid,256,0,s>>>(A2,featg,WC,RW,BV,nullptr,adj,nullptr,nullptr,0); break;
    case 5: st_layer<128,64,5,3><<<grid,256,0,s>>>(A2,featg,WC,RW,BV,nullptr,adj,nullptr,nullptr,0); break;
    case 6: st_layer<128,64,6,3><<<grid,256,0,s>>>(A2,featg,WC,RW,BV,nullptr,adj,nullptr,nullptr,0); break;
  }
}

extern "C" void kernel_launch(void* const* d_in, const int* in_sizes, int n_in,
                              void* d_out, int out_size, void* d_ws, size_t ws_size,
                              hipStream_t stream) {
  const float* x    = (const float*)d_in[0];
  const float* ew   = (const float*)d_in[1];
  const float* eb   = (const float*)d_in[2];
  const float* sw1  = (const float*)d_in[3];
  const float* sb1  = (const float*)d_in[4];
  const float* tw1  = (const float*)d_in[5];
  const float* tb1  = (const float*)d_in[6];
  const float* bg1  = (const float*)d_in[7];
  const float* bb1  = (const float*)d_in[8];
  const float* rw2  = (const float*)d_in[9];
  const float* rb2  = (const float*)d_in[10];
  const float* rg2  = (const float*)d_in[11];
  const float* rbb2 = (const float*)d_in[12];
  const float* sw2  = (const float*)d_in[13];
  const float* sb2  = (const float*)d_in[14];
  const float* tw2  = (const float*)d_in[15];
  const float* tb2  = (const float*)d_in[16];
  const float* bg2  = (const float*)d_in[17];
  const float* bb2  = (const float*)d_in[18];
  const float* rw3  = (const float*)d_in[19];
  const float* rb3  = (const float*)d_in[20];
  const float* rg3  = (const float*)d_in[21];
  const float* rbb3 = (const float*)d_in[22];
  const float* sw3  = (const float*)d_in[23];
  const float* sb3  = (const float*)d_in[24];
  const float* tw3  = (const float*)d_in[25];
  const float* tb3  = (const float*)d_in[26];
  const float* bg3  = (const float*)d_in[27];
  const float* bb3  = (const float*)d_in[28];
  const float* cbs  = (const float*)d_in[29];
  float* dout = (float*)d_out;
  float* ws = (float*)d_ws;

  const size_t OFF_ADJ = 0;
  const size_t OFF_WC1 = 256;
  const size_t OFF_B1  = 61696;
  const size_t OFF_RS1 = 62976;
  const size_t OFF_WC2 = 63296;
  const size_t OFF_RW2 = 186176;
  const size_t OFF_B2  = 227136;
  const size_t OFF_WC3 = 229696;
  const size_t OFF_RW3 = 352576;
  const size_t OFF_B3  = 393536;
  const size_t OFF_FEAT= 394816;
  const size_t OFF_A1  = 415296;
  const size_t OFF_A2  = 6706752;
  const size_t WS_FLOATS = 19289664;
  if (ws_size < WS_FLOATS*sizeof(float)) return; // insufficient workspace -> fail loudly at validation

  float* adj5 = ws + OFF_ADJ;
  float* WC1  = ws + OFF_WC1;  float* B1 = ws + OFF_B1;  float* RS1 = ws + OFF_RS1;
  float* WC2  = ws + OFF_WC2;  float* RW2 = ws + OFF_RW2; float* B2 = ws + OFF_B2;
  float* WC3  = ws + OFF_WC3;  float* RW3 = ws + OFF_RW3; float* B3 = ws + OFF_B3;
  float* feat = ws + OFF_FEAT;
  float* A1   = ws + OFF_A1;
  float* A2   = ws + OFF_A2;

  // prep-phase scratch aliased into the A2 region (dead until st2 writes it)
  float* twT1 = A2;            // 61440
  float* twT2 = A2 + 61440;    // 245760
  float* twT3 = A2 + 307200;   // 61440
  float* swe1 = A2 + 368640;   // 20480
  float* swe2 = A2 + 389120;   // 40960
  float* swe3 = A2 + 430080;   // 40960

  zero_kernel<<<80, 256, 0, stream>>>(feat, dout + 20480);
  adj_kernel<<<1, 64, 0, stream>>>(adj5);
  fold_swe<<<400, 256, 0, stream>>>(sw1, sw2, sw3, swe1, swe2, swe3);
  transpose_tw<64,64>  <<<240, 256, 0, stream>>>(tw1, twT1);
  transpose_tw<128,128><<<960, 256, 0, stream>>>(tw2, twT2);
  transpose_tw<64,64>  <<<240, 256, 0, stream>>>(tw3, twT3);
  prep_gemm<64,64,64>  <<<dim3(5,3,16), 256, 0, stream>>>(twT1, swe1, bg1, WC1);
  prep_gemm<128,64,128><<<dim3(5,3,32), 256, 0, stream>>>(twT2, swe2, bg2, WC2);
  prep_gemm<64,128,64> <<<dim3(5,3,32), 256, 0, stream>>>(twT3, swe3, bg3, WC3);
  prep_rw<<<320, 256, 0, stream>>>(rw2, rg2, bg2, rw3, rg3, bg3, RW2, RW3);
  prep_bias<<<dim3(5,3), 128, 0, stream>>>(twT1, twT2, twT3,
      sb1, tb1, bg1, bb1,
      sb2, tb2, bg2, bb2, rb2, rg2, rbb2,
      sb3, tb3, bg3, bb3, rb3, rg3, rbb3,
      B1, RS1, B2, B3);

  const int h_gn[5] = {5,6,6,4,4};
  const int h_gstart[5] = {0,5,11,17,21};
  for (int g=0; g<5; g++){
    int nj = h_gn[g];
    launch_st1(nj, stream, x, A1, WC1 + (size_t)g*12288, B1 + g*256, RS1 + g*64,
               adj5 + g*36, ew, eb, h_gstart[g]);
    launch_st2(nj, stream, A1, A2, WC2 + (size_t)g*24576, RW2 + (size_t)g*8192,
               B2 + g*512, adj5 + g*36);
    launch_st3(nj, stream, A2, feat + (size_t)g*4096, WC3 + (size_t)g*24576,
               RW3 + (size_t)g*8192, B3 + g*256, adj5 + g*36);
  }
  vq_kernel<<<dim3(B_,5), 128, 0, stream>>>(feat, cbs, dout);
}